// Round 1
// baseline (777.797 us; speedup 1.0000x reference)
//
#include <hip/hip_runtime.h>

#define WG 256

// ---------------------------------------------------------------- degree
__global__ __launch_bounds__(WG) void k_deg_init(int* __restrict__ deg, int n) {
    int i = blockIdx.x * WG + threadIdx.x;
    if (i < n) deg[i] = 1;  // self-loop
}

__global__ __launch_bounds__(WG) void k_deg_count(const int* __restrict__ dst,
                                                  int* __restrict__ deg, int e) {
    int i = blockIdx.x * WG + threadIdx.x;
    if (i < e) atomicAdd(&deg[dst[i]], 1);
}

__global__ __launch_bounds__(WG) void k_dinv(const int* __restrict__ deg,
                                             float* __restrict__ dinv, int n) {
    int i = blockIdx.x * WG + threadIdx.x;
    if (i < n) dinv[i] = rsqrtf((float)deg[i]);  // deg >= 1 always
}

// ------------------------------------------- C[n,128] = A[n,128] @ W[128,128]
// Block: 256 threads, 32 rows/block. W (64KB) + A-tile (16KB) in LDS.
// Thread (cx,ry): cols 4*cx..4*cx+3, rows ry*4..ry*4+3 -> 16 accs, 2048 FMA.
__global__ __launch_bounds__(WG) void k_gemm128(const float* __restrict__ A,
                                                const float* __restrict__ W,
                                                float* __restrict__ C, int n) {
    __shared__ float Ws[128][128];
    __shared__ float As[32][128];
    const int tid = threadIdx.x;
    const float4* W4 = (const float4*)W;
    float4* Ws4 = (float4*)&Ws[0][0];
    for (int f = tid; f < 128 * 32; f += WG) Ws4[f] = W4[f];
    const int row0 = blockIdx.x * 32;
    float4* As4 = (float4*)&As[0][0];
    for (int f = tid; f < 32 * 32; f += WG) {
        int r = f >> 5;
        float4 v = make_float4(0.f, 0.f, 0.f, 0.f);
        if (row0 + r < n) v = ((const float4*)A)[(size_t)(row0 + r) * 32 + (f & 31)];
        As4[f] = v;
    }
    __syncthreads();
    const int cx = tid & 31, ry = tid >> 5;
    float acc[4][4];
#pragma unroll
    for (int i = 0; i < 4; ++i)
#pragma unroll
        for (int j = 0; j < 4; ++j) acc[i][j] = 0.f;
    for (int k = 0; k < 128; ++k) {
        float4 w = *(const float4*)&Ws[k][cx * 4];
#pragma unroll
        for (int i = 0; i < 4; ++i) {
            float a = As[ry * 4 + i][k];
            acc[i][0] = fmaf(a, w.x, acc[i][0]);
            acc[i][1] = fmaf(a, w.y, acc[i][1]);
            acc[i][2] = fmaf(a, w.z, acc[i][2]);
            acc[i][3] = fmaf(a, w.w, acc[i][3]);
        }
    }
#pragma unroll
    for (int i = 0; i < 4; ++i) {
        int r = row0 + ry * 4 + i;
        if (r < n)
            *(float4*)&C[(size_t)r * 128 + cx * 4] =
                make_float4(acc[i][0], acc[i][1], acc[i][2], acc[i][3]);
    }
}

// ------------------------- out_h[i] = h0[i] * dinv[i]^2 + b_gcn (self-loop)
__global__ __launch_bounds__(WG) void k_agg_init(const float* __restrict__ h0,
                                                 const float* __restrict__ dinv,
                                                 const float* __restrict__ bg,
                                                 float* __restrict__ outh, int n) {
    int t = blockIdx.x * WG + threadIdx.x;  // over n*32 float4s
    if (t >= n * 32) return;
    int i = t >> 5;
    float dv = dinv[i];
    float s = dv * dv;
    float4 h = ((const float4*)h0)[t];
    float4 b = ((const float4*)bg)[t & 31];
    ((float4*)outh)[t] = make_float4(fmaf(h.x, s, b.x), fmaf(h.y, s, b.y),
                                     fmaf(h.z, s, b.z), fmaf(h.w, s, b.w));
}

// ---------------- out_h[dst] += h0[src] * dinv[src]*dinv[dst]  (128 lanes/edge)
__global__ __launch_bounds__(WG) void k_scatter(const float* __restrict__ h0,
                                                const float* __restrict__ dinv,
                                                const int* __restrict__ src,
                                                const int* __restrict__ dst,
                                                float* __restrict__ outh, int e) {
    int t = blockIdx.x * WG + threadIdx.x;
    int ei = t >> 7, c = t & 127;
    if (ei >= e) return;
    int s = src[ei], d = dst[ei];
    float w = dinv[s] * dinv[d];
    unsafeAtomicAdd(&outh[(size_t)d * 128 + c], h0[(size_t)s * 128 + c] * w);
}

// --------- logit[p] = relu(U[a]+V[b]+b1) . W2 + b2 ; one wave64 per pair
__global__ __launch_bounds__(WG) void k_pair(const float* __restrict__ U,
                                             const float* __restrict__ V,
                                             const float* __restrict__ b1,
                                             const float* __restrict__ W2,
                                             const float* __restrict__ b2,
                                             const int* __restrict__ pairs,
                                             float* __restrict__ out_logit,
                                             float* __restrict__ out_pairs, int p) {
    int w = (blockIdx.x * WG + threadIdx.x) >> 6;
    int lane = threadIdx.x & 63;
    if (w >= p) return;
    int a = pairs[2 * w], b = pairs[2 * w + 1];
    int c0 = lane, c1 = lane + 64;
    float z0 = fmaxf(U[(size_t)a * 128 + c0] + V[(size_t)b * 128 + c0] + b1[c0], 0.f);
    float z1 = fmaxf(U[(size_t)a * 128 + c1] + V[(size_t)b * 128 + c1] + b1[c1], 0.f);
    float part = fmaf(z0, W2[c0], z1 * W2[c1]);
#pragma unroll
    for (int off = 32; off > 0; off >>= 1) part += __shfl_down(part, off, 64);
    if (lane == 0) {
        out_logit[w] = part + b2[0];
        out_pairs[2 * w] = (float)a;
        out_pairs[2 * w + 1] = (float)b;
    }
}

extern "C" void kernel_launch(void* const* d_in, const int* in_sizes, int n_in,
                              void* d_out, int out_size, void* d_ws, size_t ws_size,
                              hipStream_t stream) {
    const float* x     = (const float*)d_in[0];
    const int*   eidx  = (const int*)d_in[1];
    const int*   pairs = (const int*)d_in[2];
    const float* W_gcn = (const float*)d_in[3];
    const float* b_gcn = (const float*)d_in[4];
    const float* W1    = (const float*)d_in[5];
    const float* b1    = (const float*)d_in[6];
    const float* W2    = (const float*)d_in[7];
    const float* b2    = (const float*)d_in[8];

    const int N = in_sizes[0] / 128;
    const int E = in_sizes[1] / 2;
    const int P = in_sizes[2] / 2;
    const int* esrc = eidx;
    const int* edst = eidx + E;

    // workspace layout (floats): [deg:int 50k][pad][dinv 50k][pad][h0/U 6.4M][V 6.4M]
    float* ws   = (float*)d_ws;
    int*   deg  = (int*)d_ws;
    float* dinv = ws + 65536;
    float* h0   = ws + 131072;
    float* U    = h0;                      // h0 dead after scatter; reuse for U
    float* V    = h0 + (size_t)N * 128;

    float* out_logit = (float*)d_out;      // [P]
    float* out_pairs = out_logit + P;      // [2P] as float
    float* out_h     = out_logit + 3 * (size_t)P;  // [N*128]

    dim3 blk(WG);
    k_deg_init <<<(N + WG - 1) / WG, blk, 0, stream>>>(deg, N);
    k_deg_count<<<(E + WG - 1) / WG, blk, 0, stream>>>(edst, deg, E);
    k_dinv     <<<(N + WG - 1) / WG, blk, 0, stream>>>(deg, dinv, N);
    k_gemm128  <<<(N + 31) / 32,     blk, 0, stream>>>(x, W_gcn, h0, N);
    k_agg_init <<<(N * 32 + WG - 1) / WG, blk, 0, stream>>>(h0, dinv, b_gcn, out_h, N);
    k_scatter  <<<((size_t)E * 128 + WG - 1) / WG, blk, 0, stream>>>(h0, dinv, esrc, edst, out_h, E);
    // U = out_h @ W1[:128,:] ; V = out_h @ W1[128:,:]
    k_gemm128  <<<(N + 31) / 32, blk, 0, stream>>>(out_h, W1, U, N);
    k_gemm128  <<<(N + 31) / 32, blk, 0, stream>>>(out_h, W1 + 128 * 128, V, N);
    k_pair     <<<((size_t)P * 64 + WG - 1) / WG, blk, 0, stream>>>(U, V, b1, W2, b2, pairs,
                                                                    out_logit, out_pairs, P);
}

// Round 2
// 633.049 us; speedup vs baseline: 1.2287x; 1.2287x over previous
//
#include <hip/hip_runtime.h>

#define WG 256

// ---------------------------------------------------------------- degree
__global__ __launch_bounds__(WG) void k_deg_init(int* __restrict__ deg, int n) {
    int i = blockIdx.x * WG + threadIdx.x;
    if (i < n) deg[i] = 1;  // self-loop
}

__global__ __launch_bounds__(WG) void k_deg_count(const int* __restrict__ dst,
                                                  int* __restrict__ deg, int e) {
    int i = blockIdx.x * WG + threadIdx.x;
    if (i < e) atomicAdd(&deg[dst[i]], 1);
}

__global__ __launch_bounds__(WG) void k_dinv(const int* __restrict__ deg,
                                             float* __restrict__ dinv, int n) {
    int i = blockIdx.x * WG + threadIdx.x;
    if (i < n) dinv[i] = rsqrtf((float)deg[i]);  // deg >= 1 always
}

// ------------------------------------------------ CSR build: 3-step scan
// cnt[i] = deg[i]-1 (in-degree without self loop). base = exclusive scan.
__global__ __launch_bounds__(WG) void k_scan1(const int* __restrict__ deg,
                                              int* __restrict__ base,
                                              int* __restrict__ bsum, int n) {
    __shared__ int t[WG];
    int tid = threadIdx.x;
    int i = blockIdx.x * WG + tid;
    int v = (i < n) ? deg[i] - 1 : 0;
    t[tid] = v;
    __syncthreads();
    for (int o = 1; o < WG; o <<= 1) {
        int add = (tid >= o) ? t[tid - o] : 0;
        __syncthreads();
        t[tid] += add;
        __syncthreads();
    }
    if (i < n) base[i] = t[tid] - v;  // block-local exclusive
    if (tid == WG - 1) bsum[blockIdx.x] = t[WG - 1];
}

__global__ __launch_bounds__(WG) void k_scan2(int* __restrict__ bsum, int nb) {
    __shared__ int t[WG];
    int tid = threadIdx.x;
    int v = (tid < nb) ? bsum[tid] : 0;
    t[tid] = v;
    __syncthreads();
    for (int o = 1; o < WG; o <<= 1) {
        int add = (tid >= o) ? t[tid - o] : 0;
        __syncthreads();
        t[tid] += add;
        __syncthreads();
    }
    if (tid < nb) bsum[tid] = t[tid] - v;  // exclusive block offsets
}

__global__ __launch_bounds__(WG) void k_scan3(int* __restrict__ base,
                                              const int* __restrict__ bsum,
                                              int* __restrict__ cursor, int n, int e) {
    int i = blockIdx.x * WG + threadIdx.x;
    if (i < n) {
        int b = base[i] + bsum[blockIdx.x];
        base[i] = b;
        cursor[i] = b;
        if (i == n - 1) base[n] = e;  // total in-edges == E
    }
}

__global__ __launch_bounds__(WG) void k_fill(const int* __restrict__ src,
                                             const int* __restrict__ dst,
                                             const float* __restrict__ dinv,
                                             int* __restrict__ cursor,
                                             int* __restrict__ esrc,
                                             float* __restrict__ ew, int e) {
    int i = blockIdx.x * WG + threadIdx.x;
    if (i >= e) return;
    int s = src[i], d = dst[i];
    int pos = atomicAdd(&cursor[d], 1);
    esrc[pos] = s;
    ew[pos] = dinv[s] * dinv[d];
}

// ------------------------------------------- C[n,128] = A[n,128] @ W[128,128]
__global__ __launch_bounds__(WG) void k_gemm128(const float* __restrict__ A,
                                                const float* __restrict__ W,
                                                float* __restrict__ C, int n) {
    __shared__ float Ws[128][128];
    __shared__ float As[32][128];
    const int tid = threadIdx.x;
    const float4* W4 = (const float4*)W;
    float4* Ws4 = (float4*)&Ws[0][0];
    for (int f = tid; f < 128 * 32; f += WG) Ws4[f] = W4[f];
    const int row0 = blockIdx.x * 32;
    float4* As4 = (float4*)&As[0][0];
    for (int f = tid; f < 32 * 32; f += WG) {
        int r = f >> 5;
        float4 v = make_float4(0.f, 0.f, 0.f, 0.f);
        if (row0 + r < n) v = ((const float4*)A)[(size_t)(row0 + r) * 32 + (f & 31)];
        As4[f] = v;
    }
    __syncthreads();
    const int cx = tid & 31, ry = tid >> 5;
    float acc[4][4];
#pragma unroll
    for (int i = 0; i < 4; ++i)
#pragma unroll
        for (int j = 0; j < 4; ++j) acc[i][j] = 0.f;
    for (int k = 0; k < 128; ++k) {
        float4 w = *(const float4*)&Ws[k][cx * 4];
#pragma unroll
        for (int i = 0; i < 4; ++i) {
            float a = As[ry * 4 + i][k];
            acc[i][0] = fmaf(a, w.x, acc[i][0]);
            acc[i][1] = fmaf(a, w.y, acc[i][1]);
            acc[i][2] = fmaf(a, w.z, acc[i][2]);
            acc[i][3] = fmaf(a, w.w, acc[i][3]);
        }
    }
#pragma unroll
    for (int i = 0; i < 4; ++i) {
        int r = row0 + ry * 4 + i;
        if (r < n)
            *(float4*)&C[(size_t)r * 128 + cx * 4] =
                make_float4(acc[i][0], acc[i][1], acc[i][2], acc[i][3]);
    }
}

// ------------- gather: out_h[d] = h0[d]*dinv[d]^2 + b + sum_in h0[s]*w
// 128 threads per node (2 nodes per block), thread c = column c.
__global__ __launch_bounds__(WG) void k_gather(const float* __restrict__ h0,
                                               const float* __restrict__ dinv,
                                               const float* __restrict__ bg,
                                               const int* __restrict__ base,
                                               const int* __restrict__ esrc,
                                               const float* __restrict__ ew,
                                               float* __restrict__ outh, int n) {
    int node = blockIdx.x * 2 + (threadIdx.x >> 7);
    int c = threadIdx.x & 127;
    if (node >= n) return;
    float dv = dinv[node];
    float acc = fmaf(h0[(size_t)node * 128 + c], dv * dv, bg[c]);
    int j = base[node], jend = base[node + 1];
    for (; j < jend; ++j) {
        int s = esrc[j];
        acc = fmaf(h0[(size_t)s * 128 + c], ew[j], acc);
    }
    outh[(size_t)node * 128 + c] = acc;
}

// --------- logit[p] = relu(U[a]+V[b]+b1) . W2 + b2 ; one wave64 per pair
__global__ __launch_bounds__(WG) void k_pair(const float* __restrict__ U,
                                             const float* __restrict__ V,
                                             const float* __restrict__ b1,
                                             const float* __restrict__ W2,
                                             const float* __restrict__ b2,
                                             const int* __restrict__ pairs,
                                             float* __restrict__ out_logit,
                                             float* __restrict__ out_pairs, int p) {
    int w = (blockIdx.x * WG + threadIdx.x) >> 6;
    int lane = threadIdx.x & 63;
    if (w >= p) return;
    int a = pairs[2 * w], b = pairs[2 * w + 1];
    int c0 = lane, c1 = lane + 64;
    float z0 = fmaxf(U[(size_t)a * 128 + c0] + V[(size_t)b * 128 + c0] + b1[c0], 0.f);
    float z1 = fmaxf(U[(size_t)a * 128 + c1] + V[(size_t)b * 128 + c1] + b1[c1], 0.f);
    float part = fmaf(z0, W2[c0], z1 * W2[c1]);
#pragma unroll
    for (int off = 32; off > 0; off >>= 1) part += __shfl_down(part, off, 64);
    if (lane == 0) {
        out_logit[w] = part + b2[0];
        out_pairs[2 * w] = (float)a;
        out_pairs[2 * w + 1] = (float)b;
    }
}

extern "C" void kernel_launch(void* const* d_in, const int* in_sizes, int n_in,
                              void* d_out, int out_size, void* d_ws, size_t ws_size,
                              hipStream_t stream) {
    const float* x     = (const float*)d_in[0];
    const int*   eidx  = (const int*)d_in[1];
    const int*   pairs = (const int*)d_in[2];
    const float* W_gcn = (const float*)d_in[3];
    const float* b_gcn = (const float*)d_in[4];
    const float* W1    = (const float*)d_in[5];
    const float* b1    = (const float*)d_in[6];
    const float* W2    = (const float*)d_in[7];
    const float* b2    = (const float*)d_in[8];

    const int N = in_sizes[0] / 128;
    const int E = in_sizes[1] / 2;
    const int P = in_sizes[2] / 2;
    const int* esrc_in = eidx;
    const int* edst_in = eidx + E;

    // workspace layout (4-byte units)
    float* ws     = (float*)d_ws;
    int*   deg    = (int*)d_ws;                 // [N]        @ 0
    float* dinv   = ws + 65536;                 // [N]
    int*   base   = (int*)(ws + 131072);        // [N+1]
    int*   cursor = (int*)(ws + 196608);        // [N]
    int*   bsum   = (int*)(ws + 262144);        // [256]
    int*   ecsr   = (int*)(ws + 263168);        // [E]
    float* ew     = ws + 263168 + E;            // [E]
    float* h0     = ws + 263168 + 2 * (size_t)E;  // [N*128]
    float* U      = h0;                         // h0 dead after gather
    float* V      = h0 + (size_t)N * 128;       // [N*128]

    float* out_logit = (float*)d_out;           // [P]
    float* out_pairs = out_logit + P;           // [2P] as float
    float* out_h     = out_logit + 3 * (size_t)P;  // [N*128]

    const int nb = (N + WG - 1) / WG;  // 196 <= 256
    dim3 blk(WG);
    k_deg_init <<<nb, blk, 0, stream>>>(deg, N);
    k_deg_count<<<(E + WG - 1) / WG, blk, 0, stream>>>(edst_in, deg, E);
    k_dinv     <<<nb, blk, 0, stream>>>(deg, dinv, N);
    k_scan1    <<<nb, blk, 0, stream>>>(deg, base, bsum, N);
    k_scan2    <<<1,  blk, 0, stream>>>(bsum, nb);
    k_scan3    <<<nb, blk, 0, stream>>>(base, bsum, cursor, N, E);
    k_fill     <<<(E + WG - 1) / WG, blk, 0, stream>>>(esrc_in, edst_in, dinv, cursor, ecsr, ew, E);
    k_gemm128  <<<(N + 31) / 32, blk, 0, stream>>>(x, W_gcn, h0, N);
    k_gather   <<<(N + 1) / 2,   blk, 0, stream>>>(h0, dinv, b_gcn, base, ecsr, ew, out_h, N);
    // U = out_h @ W1[:128,:] ; V = out_h @ W1[128:,:]
    k_gemm128  <<<(N + 31) / 32, blk, 0, stream>>>(out_h, W1, U, N);
    k_gemm128  <<<(N + 31) / 32, blk, 0, stream>>>(out_h, W1 + 128 * 128, V, N);
    k_pair     <<<((size_t)P * 64 + WG - 1) / WG, blk, 0, stream>>>(U, V, b1, W2, b2, pairs,
                                                                    out_logit, out_pairs, P);
}

// Round 3
// 513.542 us; speedup vs baseline: 1.5146x; 1.2327x over previous
//
#include <hip/hip_runtime.h>
#include <hip/hip_fp16.h>

#define WG 256

// ---------------------------------------------------------------- degree
__global__ __launch_bounds__(WG) void k_deg_init(int* __restrict__ deg, int n) {
    int i = blockIdx.x * WG + threadIdx.x;
    if (i < n) deg[i] = 1;  // self-loop
}

__global__ __launch_bounds__(WG) void k_deg_count(const int* __restrict__ dst,
                                                  int* __restrict__ deg, int e) {
    int i = blockIdx.x * WG + threadIdx.x;
    if (i < e) atomicAdd(&deg[dst[i]], 1);
}

__global__ __launch_bounds__(WG) void k_dinv(const int* __restrict__ deg,
                                             float* __restrict__ dinv, int n) {
    int i = blockIdx.x * WG + threadIdx.x;
    if (i < n) dinv[i] = rsqrtf((float)deg[i]);  // deg >= 1 always
}

// ------------------------------------------------ CSR build: 3-step scan
__global__ __launch_bounds__(WG) void k_scan1(const int* __restrict__ deg,
                                              int* __restrict__ base,
                                              int* __restrict__ bsum, int n) {
    __shared__ int t[WG];
    int tid = threadIdx.x;
    int i = blockIdx.x * WG + tid;
    int v = (i < n) ? deg[i] - 1 : 0;
    t[tid] = v;
    __syncthreads();
    for (int o = 1; o < WG; o <<= 1) {
        int add = (tid >= o) ? t[tid - o] : 0;
        __syncthreads();
        t[tid] += add;
        __syncthreads();
    }
    if (i < n) base[i] = t[tid] - v;  // block-local exclusive
    if (tid == WG - 1) bsum[blockIdx.x] = t[WG - 1];
}

__global__ __launch_bounds__(WG) void k_scan2(int* __restrict__ bsum, int nb) {
    __shared__ int t[WG];
    int tid = threadIdx.x;
    int v = (tid < nb) ? bsum[tid] : 0;
    t[tid] = v;
    __syncthreads();
    for (int o = 1; o < WG; o <<= 1) {
        int add = (tid >= o) ? t[tid - o] : 0;
        __syncthreads();
        t[tid] += add;
        __syncthreads();
    }
    if (tid < nb) bsum[tid] = t[tid] - v;  // exclusive block offsets
}

__global__ __launch_bounds__(WG) void k_scan3(int* __restrict__ base,
                                              const int* __restrict__ bsum,
                                              int* __restrict__ cursor, int n, int e) {
    int i = blockIdx.x * WG + threadIdx.x;
    if (i < n) {
        int b = base[i] + bsum[blockIdx.x];
        base[i] = b;
        cursor[i] = b;
        if (i == n - 1) base[n] = e;
    }
}

__global__ __launch_bounds__(WG) void k_fill(const int* __restrict__ src,
                                             const int* __restrict__ dst,
                                             const float* __restrict__ dinv,
                                             int* __restrict__ cursor,
                                             int* __restrict__ esrc,
                                             float* __restrict__ ew, int e) {
    int i = blockIdx.x * WG + threadIdx.x;
    if (i >= e) return;
    int s = src[i], d = dst[i];
    int pos = atomicAdd(&cursor[d], 1);
    esrc[pos] = s;
    ew[pos] = dinv[s] * dinv[d];
}

// ------------------------------------------- C[n,128] = A[n,128] @ W[128,128]
__global__ __launch_bounds__(WG) void k_gemm128(const float* __restrict__ A,
                                                const float* __restrict__ W,
                                                float* __restrict__ C, int n) {
    __shared__ float Ws[128][128];
    __shared__ float As[32][128];
    const int tid = threadIdx.x;
    const float4* W4 = (const float4*)W;
    float4* Ws4 = (float4*)&Ws[0][0];
    for (int f = tid; f < 128 * 32; f += WG) Ws4[f] = W4[f];
    const int row0 = blockIdx.x * 32;
    float4* As4 = (float4*)&As[0][0];
    for (int f = tid; f < 32 * 32; f += WG) {
        int r = f >> 5;
        float4 v = make_float4(0.f, 0.f, 0.f, 0.f);
        if (row0 + r < n) v = ((const float4*)A)[(size_t)(row0 + r) * 32 + (f & 31)];
        As4[f] = v;
    }
    __syncthreads();
    const int cx = tid & 31, ry = tid >> 5;
    float acc[4][4];
#pragma unroll
    for (int i = 0; i < 4; ++i)
#pragma unroll
        for (int j = 0; j < 4; ++j) acc[i][j] = 0.f;
    for (int k = 0; k < 128; ++k) {
        float4 w = *(const float4*)&Ws[k][cx * 4];
#pragma unroll
        for (int i = 0; i < 4; ++i) {
            float a = As[ry * 4 + i][k];
            acc[i][0] = fmaf(a, w.x, acc[i][0]);
            acc[i][1] = fmaf(a, w.y, acc[i][1]);
            acc[i][2] = fmaf(a, w.z, acc[i][2]);
            acc[i][3] = fmaf(a, w.w, acc[i][3]);
        }
    }
#pragma unroll
    for (int i = 0; i < 4; ++i) {
        int r = row0 + ry * 4 + i;
        if (r < n)
            *(float4*)&C[(size_t)r * 128 + cx * 4] =
                make_float4(acc[i][0], acc[i][1], acc[i][2], acc[i][3]);
    }
}

// ---------- C_packed[n][64] half2 = (col c (+bias), col c+64 (+bias)) of A@W
// Thread cx owns cols {2cx, 2cx+1, 2cx+64, 2cx+65}; pairs (c, c+64) into half2.
__global__ __launch_bounds__(WG) void k_gemm_pack(const float* __restrict__ A,
                                                  const float* __restrict__ W,
                                                  const float* __restrict__ bias,
                                                  __half2* __restrict__ Out, int n) {
    __shared__ float Ws[128][128];
    __shared__ float As[32][128];
    const int tid = threadIdx.x;
    const float4* W4 = (const float4*)W;
    float4* Ws4 = (float4*)&Ws[0][0];
    for (int f = tid; f < 128 * 32; f += WG) Ws4[f] = W4[f];
    const int row0 = blockIdx.x * 32;
    float4* As4 = (float4*)&As[0][0];
    for (int f = tid; f < 32 * 32; f += WG) {
        int r = f >> 5;
        float4 v = make_float4(0.f, 0.f, 0.f, 0.f);
        if (row0 + r < n) v = ((const float4*)A)[(size_t)(row0 + r) * 32 + (f & 31)];
        As4[f] = v;
    }
    __syncthreads();
    const int cx = tid & 31, ry = tid >> 5;
    float acc[4][4];
#pragma unroll
    for (int i = 0; i < 4; ++i)
#pragma unroll
        for (int j = 0; j < 4; ++j) acc[i][j] = 0.f;
    for (int k = 0; k < 128; ++k) {
        float2 wa = *(const float2*)&Ws[k][2 * cx];
        float2 wb = *(const float2*)&Ws[k][2 * cx + 64];
#pragma unroll
        for (int i = 0; i < 4; ++i) {
            float a = As[ry * 4 + i][k];
            acc[i][0] = fmaf(a, wa.x, acc[i][0]);
            acc[i][1] = fmaf(a, wa.y, acc[i][1]);
            acc[i][2] = fmaf(a, wb.x, acc[i][2]);
            acc[i][3] = fmaf(a, wb.y, acc[i][3]);
        }
    }
    float b0 = 0.f, b1v = 0.f, b2v = 0.f, b3v = 0.f;
    if (bias) {
        b0 = bias[2 * cx];      b1v = bias[2 * cx + 1];
        b2v = bias[2 * cx + 64]; b3v = bias[2 * cx + 65];
    }
#pragma unroll
    for (int i = 0; i < 4; ++i) {
        int r = row0 + ry * 4 + i;
        if (r < n) {
            __half2 p[2];
            p[0] = __floats2half2_rn(acc[i][0] + b0, acc[i][2] + b2v);
            p[1] = __floats2half2_rn(acc[i][1] + b1v, acc[i][3] + b3v);
            *(float2*)&Out[(size_t)r * 64 + 2 * cx] = *(float2*)p;
        }
    }
}

// ------------- gather: out_h[d] = h0[d]*dinv[d]^2 + b + sum_in h0[s]*w
__global__ __launch_bounds__(WG) void k_gather(const float* __restrict__ h0,
                                               const float* __restrict__ dinv,
                                               const float* __restrict__ bg,
                                               const int* __restrict__ base,
                                               const int* __restrict__ esrc,
                                               const float* __restrict__ ew,
                                               float* __restrict__ outh, int n) {
    int node = blockIdx.x * 2 + (threadIdx.x >> 7);
    int c = threadIdx.x & 127;
    if (node >= n) return;
    float dv = dinv[node];
    float acc = fmaf(h0[(size_t)node * 128 + c], dv * dv, bg[c]);
    int j = base[node], jend = base[node + 1];
    for (; j < jend; ++j) {
        int s = esrc[j];
        acc = fmaf(h0[(size_t)s * 128 + c], ew[j], acc);
    }
    outh[(size_t)node * 128 + c] = acc;
}

// --------- 4 pairs per wave64: logit = relu(U[a]+V[b]).W2 + b2 (b1 in U)
__global__ __launch_bounds__(WG) void k_pair4(const __half2* __restrict__ U,
                                              const __half2* __restrict__ V,
                                              const float* __restrict__ W2,
                                              const float* __restrict__ b2,
                                              const int* __restrict__ pairs,
                                              float* __restrict__ out_logit, int p) {
    int wv = (blockIdx.x * WG + threadIdx.x) >> 6;
    int lane = threadIdx.x & 63;
    int q = wv * 4;
    if (q >= p) return;
    float w2a = W2[lane], w2b = W2[lane + 64];
    float part[4];
    if (q + 4 <= p) {
        int4 pA = *(const int4*)&pairs[2 * q];      // a0 b0 a1 b1
        int4 pB = *(const int4*)&pairs[2 * q + 4];  // a2 b2 a3 b3
        int a[4] = {pA.x, pA.z, pB.x, pB.z};
        int b[4] = {pA.y, pA.w, pB.y, pB.w};
        __half2 us[4], vs[4];
#pragma unroll
        for (int j = 0; j < 4; ++j) {
            us[j] = U[(size_t)a[j] * 64 + lane];
            vs[j] = V[(size_t)b[j] * 64 + lane];
        }
#pragma unroll
        for (int j = 0; j < 4; ++j) {
            float zx = fmaxf(__low2float(us[j]) + __low2float(vs[j]), 0.f);
            float zy = fmaxf(__high2float(us[j]) + __high2float(vs[j]), 0.f);
            part[j] = fmaf(zx, w2a, zy * w2b);
        }
    } else {
#pragma unroll
        for (int j = 0; j < 4; ++j) {
            if (q + j < p) {
                int a = pairs[2 * (q + j)], b = pairs[2 * (q + j) + 1];
                __half2 u = U[(size_t)a * 64 + lane];
                __half2 v = V[(size_t)b * 64 + lane];
                float zx = fmaxf(__low2float(u) + __low2float(v), 0.f);
                float zy = fmaxf(__high2float(u) + __high2float(v), 0.f);
                part[j] = fmaf(zx, w2a, zy * w2b);
            } else part[j] = 0.f;
        }
    }
#pragma unroll
    for (int off = 32; off; off >>= 1)
#pragma unroll
        for (int j = 0; j < 4; ++j) part[j] += __shfl_down(part[j], off, 64);
    if (lane == 0) {
        float bb = b2[0];
        if (q + 4 <= p) {
            *(float4*)&out_logit[q] =
                make_float4(part[0] + bb, part[1] + bb, part[2] + bb, part[3] + bb);
        } else {
            for (int j = 0; j < 4 && q + j < p; ++j) out_logit[q + j] = part[j] + bb;
        }
    }
}

// --------- out_pairs[i] = (float)pairs[i], vectorized
__global__ __launch_bounds__(WG) void k_cvtpairs(const int* __restrict__ pairs,
                                                 float* __restrict__ outp, int n4) {
    int i = blockIdx.x * WG + threadIdx.x;  // over int4 groups
    if (i >= n4) return;
    int4 v = ((const int4*)pairs)[i];
    ((float4*)outp)[i] = make_float4((float)v.x, (float)v.y, (float)v.z, (float)v.w);
}

extern "C" void kernel_launch(void* const* d_in, const int* in_sizes, int n_in,
                              void* d_out, int out_size, void* d_ws, size_t ws_size,
                              hipStream_t stream) {
    const float* x     = (const float*)d_in[0];
    const int*   eidx  = (const int*)d_in[1];
    const int*   pairs = (const int*)d_in[2];
    const float* W_gcn = (const float*)d_in[3];
    const float* b_gcn = (const float*)d_in[4];
    const float* W1    = (const float*)d_in[5];
    const float* b1    = (const float*)d_in[6];
    const float* W2    = (const float*)d_in[7];
    const float* b2    = (const float*)d_in[8];

    const int N = in_sizes[0] / 128;
    const int E = in_sizes[1] / 2;
    const int P = in_sizes[2] / 2;
    const int* esrc_in = eidx;
    const int* edst_in = eidx + E;

    // workspace layout (4-byte units)
    float* ws     = (float*)d_ws;
    int*   deg    = (int*)d_ws;                   // [N]
    float* dinv   = ws + 65536;                   // [N]
    int*   base   = (int*)(ws + 131072);          // [N+1]
    int*   cursor = (int*)(ws + 196608);          // [N]
    int*   bsum   = (int*)(ws + 262144);          // [256]
    int*   ecsr   = (int*)(ws + 263168);          // [E]
    float* ew     = ws + 263168 + E;              // [E]
    float* h0     = ws + 263168 + 2 * (size_t)E;  // [N*128]
    __half2* Upk  = (__half2*)(h0 + (size_t)N * 128);  // [N*64]
    __half2* Vpk  = Upk + (size_t)N * 64;              // [N*64]

    float* out_logit = (float*)d_out;             // [P]
    float* out_pairs = out_logit + P;             // [2P] as float
    float* out_h     = out_logit + 3 * (size_t)P; // [N*128]

    const int nb = (N + WG - 1) / WG;  // 196 <= 256
    dim3 blk(WG);
    k_deg_init <<<nb, blk, 0, stream>>>(deg, N);
    k_deg_count<<<(E + WG - 1) / WG, blk, 0, stream>>>(edst_in, deg, E);
    k_dinv     <<<nb, blk, 0, stream>>>(deg, dinv, N);
    k_scan1    <<<nb, blk, 0, stream>>>(deg, base, bsum, N);
    k_scan2    <<<1,  blk, 0, stream>>>(bsum, nb);
    k_scan3    <<<nb, blk, 0, stream>>>(base, bsum, cursor, N, E);
    k_fill     <<<(E + WG - 1) / WG, blk, 0, stream>>>(esrc_in, edst_in, dinv, cursor, ecsr, ew, E);
    k_gemm128  <<<(N + 31) / 32, blk, 0, stream>>>(x, W_gcn, h0, N);
    k_gather   <<<(N + 1) / 2,   blk, 0, stream>>>(h0, dinv, b_gcn, base, ecsr, ew, out_h, N);
    // Upk = pack(out_h @ W1[:128,:] + b1), Vpk = pack(out_h @ W1[128:,:])
    k_gemm_pack<<<(N + 31) / 32, blk, 0, stream>>>(out_h, W1, b1, Upk, N);
    k_gemm_pack<<<(N + 31) / 32, blk, 0, stream>>>(out_h, W1 + 128 * 128, (const float*)nullptr, Vpk, N);
    k_cvtpairs <<<(P / 2 + WG - 1) / WG, blk, 0, stream>>>(pairs, out_pairs, P / 2);
    k_pair4    <<<(((P + 3) / 4) * 64 + WG - 1) / WG, blk, 0, stream>>>(Upk, Vpk, W2, b2, pairs,
                                                                        out_logit, P);
}

// Round 4
// 435.622 us; speedup vs baseline: 1.7855x; 1.1789x over previous
//
#include <hip/hip_runtime.h>
#include <hip/hip_fp16.h>

#define WG 256

// ---------------------------------------------------------------- degree
__global__ __launch_bounds__(WG) void k_deg_init(int* __restrict__ deg, int n) {
    int i = blockIdx.x * WG + threadIdx.x;
    if (i < n) deg[i] = 1;  // self-loop
}

__global__ __launch_bounds__(WG) void k_deg_count(const int* __restrict__ dst,
                                                  int* __restrict__ deg, int e) {
    int i = blockIdx.x * WG + threadIdx.x;
    if (i < e) atomicAdd(&deg[dst[i]], 1);
}

__global__ __launch_bounds__(WG) void k_dinv(const int* __restrict__ deg,
                                             float* __restrict__ dinv, int n) {
    int i = blockIdx.x * WG + threadIdx.x;
    if (i < n) dinv[i] = rsqrtf((float)deg[i]);  // deg >= 1 always
}

// ------------------------------------------------ CSR build: 3-step scan
__global__ __launch_bounds__(WG) void k_scan1(const int* __restrict__ deg,
                                              int* __restrict__ base,
                                              int* __restrict__ bsum, int n) {
    __shared__ int t[WG];
    int tid = threadIdx.x;
    int i = blockIdx.x * WG + tid;
    int v = (i < n) ? deg[i] - 1 : 0;
    t[tid] = v;
    __syncthreads();
    for (int o = 1; o < WG; o <<= 1) {
        int add = (tid >= o) ? t[tid - o] : 0;
        __syncthreads();
        t[tid] += add;
        __syncthreads();
    }
    if (i < n) base[i] = t[tid] - v;  // block-local exclusive
    if (tid == WG - 1) bsum[blockIdx.x] = t[WG - 1];
}

__global__ __launch_bounds__(WG) void k_scan2(int* __restrict__ bsum, int nb) {
    __shared__ int t[WG];
    int tid = threadIdx.x;
    int v = (tid < nb) ? bsum[tid] : 0;
    t[tid] = v;
    __syncthreads();
    for (int o = 1; o < WG; o <<= 1) {
        int add = (tid >= o) ? t[tid - o] : 0;
        __syncthreads();
        t[tid] += add;
        __syncthreads();
    }
    if (tid < nb) bsum[tid] = t[tid] - v;  // exclusive block offsets
}

__global__ __launch_bounds__(WG) void k_scan3(int* __restrict__ base,
                                              const int* __restrict__ bsum,
                                              int* __restrict__ cursor, int n, int e) {
    int i = blockIdx.x * WG + threadIdx.x;
    if (i < n) {
        int b = base[i] + bsum[blockIdx.x];
        base[i] = b;
        cursor[i] = b;
        if (i == n - 1) base[n] = e;
    }
}

__global__ __launch_bounds__(WG) void k_fill(const int* __restrict__ src,
                                             const int* __restrict__ dst,
                                             const float* __restrict__ dinv,
                                             int* __restrict__ cursor,
                                             int* __restrict__ esrc,
                                             float* __restrict__ ew, int e) {
    int i = blockIdx.x * WG + threadIdx.x;
    if (i >= e) return;
    int s = src[i], d = dst[i];
    int pos = atomicAdd(&cursor[d], 1);
    esrc[pos] = s;
    ew[pos] = dinv[s] * dinv[d];
}

// ------------------------------------------- C[n,128] = A[n,128] @ W[128,128]
__global__ __launch_bounds__(WG) void k_gemm128(const float* __restrict__ A,
                                                const float* __restrict__ W,
                                                float* __restrict__ C, int n) {
    __shared__ float Ws[128][128];
    __shared__ float As[32][128];
    const int tid = threadIdx.x;
    const float4* W4 = (const float4*)W;
    float4* Ws4 = (float4*)&Ws[0][0];
    for (int f = tid; f < 128 * 32; f += WG) Ws4[f] = W4[f];
    const int row0 = blockIdx.x * 32;
    float4* As4 = (float4*)&As[0][0];
    for (int f = tid; f < 32 * 32; f += WG) {
        int r = f >> 5;
        float4 v = make_float4(0.f, 0.f, 0.f, 0.f);
        if (row0 + r < n) v = ((const float4*)A)[(size_t)(row0 + r) * 32 + (f & 31)];
        As4[f] = v;
    }
    __syncthreads();
    const int cx = tid & 31, ry = tid >> 5;
    float acc[4][4];
#pragma unroll
    for (int i = 0; i < 4; ++i)
#pragma unroll
        for (int j = 0; j < 4; ++j) acc[i][j] = 0.f;
    for (int k = 0; k < 128; ++k) {
        float4 w = *(const float4*)&Ws[k][cx * 4];
#pragma unroll
        for (int i = 0; i < 4; ++i) {
            float a = As[ry * 4 + i][k];
            acc[i][0] = fmaf(a, w.x, acc[i][0]);
            acc[i][1] = fmaf(a, w.y, acc[i][1]);
            acc[i][2] = fmaf(a, w.z, acc[i][2]);
            acc[i][3] = fmaf(a, w.w, acc[i][3]);
        }
    }
#pragma unroll
    for (int i = 0; i < 4; ++i) {
        int r = row0 + ry * 4 + i;
        if (r < n)
            *(float4*)&C[(size_t)r * 128 + cx * 4] =
                make_float4(acc[i][0], acc[i][1], acc[i][2], acc[i][3]);
    }
}

// ---------- C_packed[n][64] half2 = (col c (+bias), col c+64 (+bias)) of A@W
__global__ __launch_bounds__(WG) void k_gemm_pack(const float* __restrict__ A,
                                                  const float* __restrict__ W,
                                                  const float* __restrict__ bias,
                                                  __half2* __restrict__ Out, int n) {
    __shared__ float Ws[128][128];
    __shared__ float As[32][128];
    const int tid = threadIdx.x;
    const float4* W4 = (const float4*)W;
    float4* Ws4 = (float4*)&Ws[0][0];
    for (int f = tid; f < 128 * 32; f += WG) Ws4[f] = W4[f];
    const int row0 = blockIdx.x * 32;
    float4* As4 = (float4*)&As[0][0];
    for (int f = tid; f < 32 * 32; f += WG) {
        int r = f >> 5;
        float4 v = make_float4(0.f, 0.f, 0.f, 0.f);
        if (row0 + r < n) v = ((const float4*)A)[(size_t)(row0 + r) * 32 + (f & 31)];
        As4[f] = v;
    }
    __syncthreads();
    const int cx = tid & 31, ry = tid >> 5;
    float acc[4][4];
#pragma unroll
    for (int i = 0; i < 4; ++i)
#pragma unroll
        for (int j = 0; j < 4; ++j) acc[i][j] = 0.f;
    for (int k = 0; k < 128; ++k) {
        float2 wa = *(const float2*)&Ws[k][2 * cx];
        float2 wb = *(const float2*)&Ws[k][2 * cx + 64];
#pragma unroll
        for (int i = 0; i < 4; ++i) {
            float a = As[ry * 4 + i][k];
            acc[i][0] = fmaf(a, wa.x, acc[i][0]);
            acc[i][1] = fmaf(a, wa.y, acc[i][1]);
            acc[i][2] = fmaf(a, wb.x, acc[i][2]);
            acc[i][3] = fmaf(a, wb.y, acc[i][3]);
        }
    }
    float b0 = 0.f, b1v = 0.f, b2v = 0.f, b3v = 0.f;
    if (bias) {
        b0 = bias[2 * cx];      b1v = bias[2 * cx + 1];
        b2v = bias[2 * cx + 64]; b3v = bias[2 * cx + 65];
    }
#pragma unroll
    for (int i = 0; i < 4; ++i) {
        int r = row0 + ry * 4 + i;
        if (r < n) {
            __half2 p[2];
            p[0] = __floats2half2_rn(acc[i][0] + b0, acc[i][2] + b2v);
            p[1] = __floats2half2_rn(acc[i][1] + b1v, acc[i][3] + b3v);
            *(float2*)&Out[(size_t)r * 64 + 2 * cx] = *(float2*)p;
        }
    }
}

// ------------- gather: out_h[d] = h0[d]*dinv[d]^2 + b + sum_in h0[s]*w
// One wave64 per node (4 nodes/block); lane owns cols {2c,2c+1} as float2.
// Edge loop unrolled x4: 4 independent 512B row gathers in flight per wave.
__global__ __launch_bounds__(WG) void k_gather(const float* __restrict__ h0,
                                               const float* __restrict__ dinv,
                                               const float* __restrict__ bg,
                                               const int* __restrict__ base,
                                               const int* __restrict__ esrc,
                                               const float* __restrict__ ew,
                                               float* __restrict__ outh, int n) {
    int node = blockIdx.x * 4 + (threadIdx.x >> 6);
    int lane = threadIdx.x & 63;
    if (node >= n) return;
    const float2* H2 = (const float2*)h0;
    float dv = dinv[node];
    float2 b = ((const float2*)bg)[lane];
    float2 hs = H2[(size_t)node * 64 + lane];
    float s2 = dv * dv;
    float2 acc = make_float2(fmaf(hs.x, s2, b.x), fmaf(hs.y, s2, b.y));
    int j = base[node], jend = base[node + 1];
    for (; j + 4 <= jend; j += 4) {
        int i0 = esrc[j], i1 = esrc[j + 1], i2 = esrc[j + 2], i3 = esrc[j + 3];
        float w0 = ew[j], w1 = ew[j + 1], w2 = ew[j + 2], w3 = ew[j + 3];
        float2 v0 = H2[(size_t)i0 * 64 + lane];
        float2 v1 = H2[(size_t)i1 * 64 + lane];
        float2 v2 = H2[(size_t)i2 * 64 + lane];
        float2 v3 = H2[(size_t)i3 * 64 + lane];
        acc.x = fmaf(v0.x, w0, acc.x); acc.y = fmaf(v0.y, w0, acc.y);
        acc.x = fmaf(v1.x, w1, acc.x); acc.y = fmaf(v1.y, w1, acc.y);
        acc.x = fmaf(v2.x, w2, acc.x); acc.y = fmaf(v2.y, w2, acc.y);
        acc.x = fmaf(v3.x, w3, acc.x); acc.y = fmaf(v3.y, w3, acc.y);
    }
    for (; j < jend; ++j) {
        int s = esrc[j];
        float w = ew[j];
        float2 v = H2[(size_t)s * 64 + lane];
        acc.x = fmaf(v.x, w, acc.x);
        acc.y = fmaf(v.y, w, acc.y);
    }
    ((float2*)outh)[(size_t)node * 64 + lane] = acc;
}

// --------- 4 pairs per wave64: logit = relu(U[a]+V[b]).W2 + b2 (b1 in U)
__global__ __launch_bounds__(WG) void k_pair4(const __half2* __restrict__ U,
                                              const __half2* __restrict__ V,
                                              const float* __restrict__ W2,
                                              const float* __restrict__ b2,
                                              const int* __restrict__ pairs,
                                              float* __restrict__ out_logit, int p) {
    int wv = (blockIdx.x * WG + threadIdx.x) >> 6;
    int lane = threadIdx.x & 63;
    int q = wv * 4;
    if (q >= p) return;
    float w2a = W2[lane], w2b = W2[lane + 64];
    float part[4];
    if (q + 4 <= p) {
        int4 pA = *(const int4*)&pairs[2 * q];      // a0 b0 a1 b1
        int4 pB = *(const int4*)&pairs[2 * q + 4];  // a2 b2 a3 b3
        int a[4] = {pA.x, pA.z, pB.x, pB.z};
        int b[4] = {pA.y, pA.w, pB.y, pB.w};
        __half2 us[4], vs[4];
#pragma unroll
        for (int j = 0; j < 4; ++j) {
            us[j] = U[(size_t)a[j] * 64 + lane];
            vs[j] = V[(size_t)b[j] * 64 + lane];
        }
#pragma unroll
        for (int j = 0; j < 4; ++j) {
            float zx = fmaxf(__low2float(us[j]) + __low2float(vs[j]), 0.f);
            float zy = fmaxf(__high2float(us[j]) + __high2float(vs[j]), 0.f);
            part[j] = fmaf(zx, w2a, zy * w2b);
        }
    } else {
#pragma unroll
        for (int j = 0; j < 4; ++j) {
            if (q + j < p) {
                int a = pairs[2 * (q + j)], b = pairs[2 * (q + j) + 1];
                __half2 u = U[(size_t)a * 64 + lane];
                __half2 v = V[(size_t)b * 64 + lane];
                float zx = fmaxf(__low2float(u) + __low2float(v), 0.f);
                float zy = fmaxf(__high2float(u) + __high2float(v), 0.f);
                part[j] = fmaf(zx, w2a, zy * w2b);
            } else part[j] = 0.f;
        }
    }
#pragma unroll
    for (int off = 32; off; off >>= 1)
#pragma unroll
        for (int j = 0; j < 4; ++j) part[j] += __shfl_down(part[j], off, 64);
    if (lane == 0) {
        float bb = b2[0];
        if (q + 4 <= p) {
            *(float4*)&out_logit[q] =
                make_float4(part[0] + bb, part[1] + bb, part[2] + bb, part[3] + bb);
        } else {
            for (int j = 0; j < 4 && q + j < p; ++j) out_logit[q + j] = part[j] + bb;
        }
    }
}

// --------- out_pairs[i] = (float)pairs[i], vectorized
__global__ __launch_bounds__(WG) void k_cvtpairs(const int* __restrict__ pairs,
                                                 float* __restrict__ outp, int n4) {
    int i = blockIdx.x * WG + threadIdx.x;  // over int4 groups
    if (i >= n4) return;
    int4 v = ((const int4*)pairs)[i];
    ((float4*)outp)[i] = make_float4((float)v.x, (float)v.y, (float)v.z, (float)v.w);
}

extern "C" void kernel_launch(void* const* d_in, const int* in_sizes, int n_in,
                              void* d_out, int out_size, void* d_ws, size_t ws_size,
                              hipStream_t stream) {
    const float* x     = (const float*)d_in[0];
    const int*   eidx  = (const int*)d_in[1];
    const int*   pairs = (const int*)d_in[2];
    const float* W_gcn = (const float*)d_in[3];
    const float* b_gcn = (const float*)d_in[4];
    const float* W1    = (const float*)d_in[5];
    const float* b1    = (const float*)d_in[6];
    const float* W2    = (const float*)d_in[7];
    const float* b2    = (const float*)d_in[8];

    const int N = in_sizes[0] / 128;
    const int E = in_sizes[1] / 2;
    const int P = in_sizes[2] / 2;
    const int* esrc_in = eidx;
    const int* edst_in = eidx + E;

    // workspace layout (4-byte units)
    float* ws     = (float*)d_ws;
    int*   deg    = (int*)d_ws;                   // [N]
    float* dinv   = ws + 65536;                   // [N]
    int*   base   = (int*)(ws + 131072);          // [N+1]
    int*   cursor = (int*)(ws + 196608);          // [N]
    int*   bsum   = (int*)(ws + 262144);          // [256]
    int*   ecsr   = (int*)(ws + 263168);          // [E]
    float* ew     = ws + 263168 + E;              // [E]
    float* h0     = ws + 263168 + 2 * (size_t)E;  // [N*128]
    __half2* Upk  = (__half2*)(h0 + (size_t)N * 128);  // [N*64]
    __half2* Vpk  = Upk + (size_t)N * 64;              // [N*64]

    float* out_logit = (float*)d_out;             // [P]
    float* out_pairs = out_logit + P;             // [2P] as float
    float* out_h     = out_logit + 3 * (size_t)P; // [N*128]

    const int nb = (N + WG - 1) / WG;  // 196 <= 256
    dim3 blk(WG);
    k_deg_init <<<nb, blk, 0, stream>>>(deg, N);
    k_deg_count<<<(E + WG - 1) / WG, blk, 0, stream>>>(edst_in, deg, E);
    k_dinv     <<<nb, blk, 0, stream>>>(deg, dinv, N);
    k_scan1    <<<nb, blk, 0, stream>>>(deg, base, bsum, N);
    k_scan2    <<<1,  blk, 0, stream>>>(bsum, nb);
    k_scan3    <<<nb, blk, 0, stream>>>(base, bsum, cursor, N, E);
    k_fill     <<<(E + WG - 1) / WG, blk, 0, stream>>>(esrc_in, edst_in, dinv, cursor, ecsr, ew, E);
    k_gemm128  <<<(N + 31) / 32, blk, 0, stream>>>(x, W_gcn, h0, N);
    k_gather   <<<(N + 3) / 4,   blk, 0, stream>>>(h0, dinv, b_gcn, base, ecsr, ew, out_h, N);
    // Upk = pack(out_h @ W1[:128,:] + b1), Vpk = pack(out_h @ W1[128:,:])
    k_gemm_pack<<<(N + 31) / 32, blk, 0, stream>>>(out_h, W1, b1, Upk, N);
    k_gemm_pack<<<(N + 31) / 32, blk, 0, stream>>>(out_h, W1 + 128 * 128, (const float*)nullptr, Vpk, N);
    k_cvtpairs <<<(P / 2 + WG - 1) / WG, blk, 0, stream>>>(pairs, out_pairs, P / 2);
    k_pair4    <<<(((P + 3) / 4) * 64 + WG - 1) / WG, blk, 0, stream>>>(Upk, Vpk, W2, b2, pairs,
                                                                        out_logit, P);
}

// Round 6
// 401.205 us; speedup vs baseline: 1.9387x; 1.0858x over previous
//
#include <hip/hip_runtime.h>
#include <hip/hip_fp16.h>

#define WG 256

typedef _Float16 hv2 __attribute__((ext_vector_type(2)));

// ---------------------------------------------------------------- degree
__global__ __launch_bounds__(WG) void k_deg_init(int* __restrict__ deg, int n) {
    int i = blockIdx.x * WG + threadIdx.x;
    if (i < n) deg[i] = 1;  // self-loop
}

__global__ __launch_bounds__(WG) void k_deg_count(const int* __restrict__ dst,
                                                  int* __restrict__ deg, int e) {
    int i = blockIdx.x * WG + threadIdx.x;
    if (i < e) atomicAdd(&deg[dst[i]], 1);
}

// ------------------------------------------------ CSR build: 3-step scan
// Also computes dinv = rsqrt(deg) (folded former k_dinv).
__global__ __launch_bounds__(WG) void k_scan1(const int* __restrict__ deg,
                                              float* __restrict__ dinv,
                                              int* __restrict__ base,
                                              int* __restrict__ bsum, int n) {
    __shared__ int t[WG];
    int tid = threadIdx.x;
    int i = blockIdx.x * WG + tid;
    int d = (i < n) ? deg[i] : 1;
    if (i < n) dinv[i] = rsqrtf((float)d);
    int v = (i < n) ? d - 1 : 0;
    t[tid] = v;
    __syncthreads();
    for (int o = 1; o < WG; o <<= 1) {
        int add = (tid >= o) ? t[tid - o] : 0;
        __syncthreads();
        t[tid] += add;
        __syncthreads();
    }
    if (i < n) base[i] = t[tid] - v;  // block-local exclusive
    if (tid == WG - 1) bsum[blockIdx.x] = t[WG - 1];
}

__global__ __launch_bounds__(WG) void k_scan2(int* __restrict__ bsum, int nb) {
    __shared__ int t[WG];
    int tid = threadIdx.x;
    int v = (tid < nb) ? bsum[tid] : 0;
    t[tid] = v;
    __syncthreads();
    for (int o = 1; o < WG; o <<= 1) {
        int add = (tid >= o) ? t[tid - o] : 0;
        __syncthreads();
        t[tid] += add;
        __syncthreads();
    }
    if (tid < nb) bsum[tid] = t[tid] - v;  // exclusive block offsets
}

__global__ __launch_bounds__(WG) void k_scan3(int* __restrict__ base,
                                              const int* __restrict__ bsum,
                                              int* __restrict__ cursor, int n, int e) {
    int i = blockIdx.x * WG + threadIdx.x;
    if (i < n) {
        int b = base[i] + bsum[blockIdx.x];
        base[i] = b;
        cursor[i] = b;
        if (i == n - 1) base[n] = e;
    }
}

__global__ __launch_bounds__(WG) void k_fill(const int* __restrict__ src,
                                             const int* __restrict__ dst,
                                             const float* __restrict__ dinv,
                                             int* __restrict__ cursor,
                                             int* __restrict__ esrc,
                                             float* __restrict__ ew, int e) {
    int i = blockIdx.x * WG + threadIdx.x;
    if (i >= e) return;
    int s = src[i], d = dst[i];
    int pos = atomicAdd(&cursor[d], 1);
    esrc[pos] = s;
    ew[pos] = dinv[s] * dinv[d];
}

// ---------- U/V packing: Out[r][i] = half2(col i, col i+64) of A@W (+bias)
__global__ __launch_bounds__(WG) void k_gemm_pack(const float* __restrict__ A,
                                                  const float* __restrict__ W,
                                                  const float* __restrict__ bias,
                                                  __half2* __restrict__ Out, int n) {
    __shared__ float Ws[128][128];
    __shared__ float As[32][128];
    const int tid = threadIdx.x;
    const float4* W4 = (const float4*)W;
    float4* Ws4 = (float4*)&Ws[0][0];
    for (int f = tid; f < 128 * 32; f += WG) Ws4[f] = W4[f];
    const int row0 = blockIdx.x * 32;
    float4* As4 = (float4*)&As[0][0];
    for (int f = tid; f < 32 * 32; f += WG) {
        int r = f >> 5;
        float4 v = make_float4(0.f, 0.f, 0.f, 0.f);
        if (row0 + r < n) v = ((const float4*)A)[(size_t)(row0 + r) * 32 + (f & 31)];
        As4[f] = v;
    }
    __syncthreads();
    const int cx = tid & 31, ry = tid >> 5;
    float acc[4][4];
#pragma unroll
    for (int i = 0; i < 4; ++i)
#pragma unroll
        for (int j = 0; j < 4; ++j) acc[i][j] = 0.f;
    for (int k = 0; k < 128; ++k) {
        float2 wa = *(const float2*)&Ws[k][2 * cx];
        float2 wb = *(const float2*)&Ws[k][2 * cx + 64];
#pragma unroll
        for (int i = 0; i < 4; ++i) {
            float a = As[ry * 4 + i][k];
            acc[i][0] = fmaf(a, wa.x, acc[i][0]);
            acc[i][1] = fmaf(a, wa.y, acc[i][1]);
            acc[i][2] = fmaf(a, wb.x, acc[i][2]);
            acc[i][3] = fmaf(a, wb.y, acc[i][3]);
        }
    }
    float b0 = 0.f, b1v = 0.f, b2v = 0.f, b3v = 0.f;
    if (bias) {
        b0 = bias[2 * cx];       b1v = bias[2 * cx + 1];
        b2v = bias[2 * cx + 64]; b3v = bias[2 * cx + 65];
    }
#pragma unroll
    for (int i = 0; i < 4; ++i) {
        int r = row0 + ry * 4 + i;
        if (r < n) {
            __half2 p[2];
            p[0] = __floats2half2_rn(acc[i][0] + b0, acc[i][2] + b2v);
            p[1] = __floats2half2_rn(acc[i][1] + b1v, acc[i][3] + b3v);
            *(float2*)&Out[(size_t)r * 64 + 2 * cx] = *(float2*)p;
        }
    }
}

// ---------- h0 packing: Out[r][i] = half2(col 2i, col 2i+1) of A@W (adjacent)
__global__ __launch_bounds__(WG) void k_gemm_packadj(const float* __restrict__ A,
                                                     const float* __restrict__ W,
                                                     __half2* __restrict__ Out, int n) {
    __shared__ float Ws[128][128];
    __shared__ float As[32][128];
    const int tid = threadIdx.x;
    const float4* W4 = (const float4*)W;
    float4* Ws4 = (float4*)&Ws[0][0];
    for (int f = tid; f < 128 * 32; f += WG) Ws4[f] = W4[f];
    const int row0 = blockIdx.x * 32;
    float4* As4 = (float4*)&As[0][0];
    for (int f = tid; f < 32 * 32; f += WG) {
        int r = f >> 5;
        float4 v = make_float4(0.f, 0.f, 0.f, 0.f);
        if (row0 + r < n) v = ((const float4*)A)[(size_t)(row0 + r) * 32 + (f & 31)];
        As4[f] = v;
    }
    __syncthreads();
    const int cx = tid & 31, ry = tid >> 5;
    float acc[4][4];
#pragma unroll
    for (int i = 0; i < 4; ++i)
#pragma unroll
        for (int j = 0; j < 4; ++j) acc[i][j] = 0.f;
    for (int k = 0; k < 128; ++k) {
        float2 wa = *(const float2*)&Ws[k][2 * cx];
        float2 wb = *(const float2*)&Ws[k][2 * cx + 64];
#pragma unroll
        for (int i = 0; i < 4; ++i) {
            float a = As[ry * 4 + i][k];
            acc[i][0] = fmaf(a, wa.x, acc[i][0]);
            acc[i][1] = fmaf(a, wa.y, acc[i][1]);
            acc[i][2] = fmaf(a, wb.x, acc[i][2]);
            acc[i][3] = fmaf(a, wb.y, acc[i][3]);
        }
    }
#pragma unroll
    for (int i = 0; i < 4; ++i) {
        int r = row0 + ry * 4 + i;
        if (r < n) {
            Out[(size_t)r * 64 + cx]      = __floats2half2_rn(acc[i][0], acc[i][1]);
            Out[(size_t)r * 64 + 32 + cx] = __floats2half2_rn(acc[i][2], acc[i][3]);
        }
    }
}

// ------------- gather: out_h[d] = h0[d]*dinv[d]^2 + b + sum_in h0[s]*w
// h0 is adjacent-packed half2; lane owns cols {2lane, 2lane+1}. x4 unroll.
__global__ __launch_bounds__(WG) void k_gather(const __half2* __restrict__ Hpk,
                                               const float* __restrict__ dinv,
                                               const float* __restrict__ bg,
                                               const int* __restrict__ base,
                                               const int* __restrict__ esrc,
                                               const float* __restrict__ ew,
                                               float* __restrict__ outh, int n) {
    int node = blockIdx.x * 4 + (threadIdx.x >> 6);
    int lane = threadIdx.x & 63;
    if (node >= n) return;
    float dv = dinv[node];
    float s2 = dv * dv;
    float2 b = ((const float2*)bg)[lane];
    __half2 hs = Hpk[(size_t)node * 64 + lane];
    float2 acc = make_float2(fmaf(__low2float(hs), s2, b.x),
                             fmaf(__high2float(hs), s2, b.y));
    int j = base[node], jend = base[node + 1];
    for (; j + 4 <= jend; j += 4) {
        int i0 = esrc[j], i1 = esrc[j + 1], i2 = esrc[j + 2], i3 = esrc[j + 3];
        float w0 = ew[j], w1 = ew[j + 1], w2 = ew[j + 2], w3 = ew[j + 3];
        __half2 v0 = Hpk[(size_t)i0 * 64 + lane];
        __half2 v1 = Hpk[(size_t)i1 * 64 + lane];
        __half2 v2 = Hpk[(size_t)i2 * 64 + lane];
        __half2 v3 = Hpk[(size_t)i3 * 64 + lane];
        acc.x = fmaf(__low2float(v0), w0, acc.x); acc.y = fmaf(__high2float(v0), w0, acc.y);
        acc.x = fmaf(__low2float(v1), w1, acc.x); acc.y = fmaf(__high2float(v1), w1, acc.y);
        acc.x = fmaf(__low2float(v2), w2, acc.x); acc.y = fmaf(__high2float(v2), w2, acc.y);
        acc.x = fmaf(__low2float(v3), w3, acc.x); acc.y = fmaf(__high2float(v3), w3, acc.y);
    }
    for (; j < jend; ++j) {
        int s = esrc[j];
        float w = ew[j];
        __half2 v = Hpk[(size_t)s * 64 + lane];
        acc.x = fmaf(__low2float(v), w, acc.x);
        acc.y = fmaf(__high2float(v), w, acc.y);
    }
    ((float2*)outh)[(size_t)node * 64 + lane] = acc;
}

// --------- 1 pair per 16 lanes: logit = relu(U[a]+V[b]).W2 + b2 (b1 in U)
// Lane sub owns half2 positions 4sub..4sub+3 (= cols 4sub..+3 and 4sub+64..+67).
__global__ __launch_bounds__(WG) void k_pair16(const __half2* __restrict__ U,
                                               const __half2* __restrict__ V,
                                               const float* __restrict__ W2,
                                               const float* __restrict__ b2,
                                               const int* __restrict__ pairs,
                                               float* __restrict__ out_logit, int p) {
    int wv = (blockIdx.x * WG + threadIdx.x) >> 6;
    int lane = threadIdx.x & 63;
    int g = lane >> 4, sub = lane & 15;
    int q = wv * 4 + g;
    bool valid = (q < p);
    int qa = valid ? q : 0;
    int a = pairs[2 * qa], b = pairs[2 * qa + 1];

    // W2 fragment for this lane's 8 columns, packed (col c, col c+64)
    float4 w2lo = ((const float4*)W2)[sub];
    float4 w2hi = ((const float4*)(W2 + 64))[sub];
    hv2 w2h[4];
    w2h[0] = hv2{(_Float16)w2lo.x, (_Float16)w2hi.x};
    w2h[1] = hv2{(_Float16)w2lo.y, (_Float16)w2hi.y};
    w2h[2] = hv2{(_Float16)w2lo.z, (_Float16)w2hi.z};
    w2h[3] = hv2{(_Float16)w2lo.w, (_Float16)w2hi.w};

    int4 uu = *(const int4*)(U + (size_t)a * 64 + 4 * sub);
    int4 vv = *(const int4*)(V + (size_t)b * 64 + 4 * sub);
    const int* ui = (const int*)&uu;
    const int* vi = (const int*)&vv;

    float part = 0.f;
#pragma unroll
    for (int k = 0; k < 4; ++k) {
        hv2 s = __builtin_bit_cast(hv2, ui[k]) + __builtin_bit_cast(hv2, vi[k]);
        hv2 z = __builtin_elementwise_max(s, hv2{(_Float16)0.f, (_Float16)0.f});
        part = __builtin_amdgcn_fdot2(z, w2h[k], part, false);
    }
#pragma unroll
    for (int m = 1; m < 16; m <<= 1) part += __shfl_xor(part, m, 64);
    if (sub == 0 && valid) out_logit[q] = part + b2[0];
}

// --------- out_pairs[i] = (float)pairs[i], vectorized
__global__ __launch_bounds__(WG) void k_cvtpairs(const int* __restrict__ pairs,
                                                 float* __restrict__ outp, int n4) {
    int i = blockIdx.x * WG + threadIdx.x;  // over int4 groups
    if (i >= n4) return;
    int4 v = ((const int4*)pairs)[i];
    ((float4*)outp)[i] = make_float4((float)v.x, (float)v.y, (float)v.z, (float)v.w);
}

extern "C" void kernel_launch(void* const* d_in, const int* in_sizes, int n_in,
                              void* d_out, int out_size, void* d_ws, size_t ws_size,
                              hipStream_t stream) {
    const float* x     = (const float*)d_in[0];
    const int*   eidx  = (const int*)d_in[1];
    const int*   pairs = (const int*)d_in[2];
    const float* W_gcn = (const float*)d_in[3];
    const float* b_gcn = (const float*)d_in[4];
    const float* W1    = (const float*)d_in[5];
    const float* b1    = (const float*)d_in[6];
    const float* W2    = (const float*)d_in[7];
    const float* b2    = (const float*)d_in[8];

    const int N = in_sizes[0] / 128;
    const int E = in_sizes[1] / 2;
    const int P = in_sizes[2] / 2;
    const int* esrc_in = eidx;
    const int* edst_in = eidx + E;

    // workspace layout (4-byte units)
    float* ws     = (float*)d_ws;
    int*   deg    = (int*)d_ws;                   // [N]
    float* dinv   = ws + 65536;                   // [N]
    int*   base   = (int*)(ws + 131072);          // [N+1]
    int*   cursor = (int*)(ws + 196608);          // [N]
    int*   bsum   = (int*)(ws + 262144);          // [256]
    int*   ecsr   = (int*)(ws + 263168);          // [E]
    float* ew     = ws + 263168 + E;              // [E]
    float* h0     = ws + 263168 + 2 * (size_t)E;  // region: [N*128] floats
    __half2* Hpk  = (__half2*)h0;                 // [N*64] half2 (uses part of h0 slot)
    __half2* Upk  = (__half2*)(h0 + (size_t)N * 128);  // [N*64]
    __half2* Vpk  = Upk + (size_t)N * 64;              // [N*64]

    float* out_logit = (float*)d_out;             // [P]
    float* out_pairs = out_logit + P;             // [2P] as float
    float* out_h     = out_logit + 3 * (size_t)P; // [N*128]

    const int nb = (N + WG - 1) / WG;  // 196 <= 256
    dim3 blk(WG);
    dim3 grid_pair((unsigned)((P + 15) / 16));
    k_deg_init    <<<nb, blk, 0, stream>>>(deg, N);
    k_deg_count   <<<(E + WG - 1) / WG, blk, 0, stream>>>(edst_in, deg, E);
    k_scan1       <<<nb, blk, 0, stream>>>(deg, dinv, base, bsum, N);
    k_scan2       <<<1,  blk, 0, stream>>>(bsum, nb);
    k_scan3       <<<nb, blk, 0, stream>>>(base, bsum, cursor, N, E);
    k_fill        <<<(E + WG - 1) / WG, blk, 0, stream>>>(esrc_in, edst_in, dinv, cursor, ecsr, ew, E);
    k_gemm_packadj<<<(N + 31) / 32, blk, 0, stream>>>(x, W_gcn, Hpk, N);
    k_gather      <<<(N + 3) / 4,   blk, 0, stream>>>(Hpk, dinv, b_gcn, base, ecsr, ew, out_h, N);
    // Upk = pack(out_h @ W1[:128,:] + b1), Vpk = pack(out_h @ W1[128:,:])
    k_gemm_pack   <<<(N + 31) / 32, blk, 0, stream>>>(out_h, W1, b1, Upk, N);
    k_gemm_pack   <<<(N + 31) / 32, blk, 0, stream>>>(out_h, W1 + 128 * 128, (const float*)nullptr, Vpk, N);
    k_cvtpairs    <<<(P / 2 + WG - 1) / WG, blk, 0, stream>>>(pairs, out_pairs, P / 2);
    k_pair16      <<<grid_pair, blk, 0, stream>>>(Upk, Vpk, W2, b2, pairs, out_logit, P);
}

// Round 7
// 324.965 us; speedup vs baseline: 2.3935x; 1.2346x over previous
//
#include <hip/hip_runtime.h>
#include <hip/hip_fp16.h>

#define WG 256

typedef _Float16 f16;
typedef _Float16 hv2 __attribute__((ext_vector_type(2)));
typedef _Float16 f16x4 __attribute__((ext_vector_type(4)));
typedef _Float16 f16x8 __attribute__((ext_vector_type(8)));
typedef float f32x4 __attribute__((ext_vector_type(4)));

// ---------------------------------------------------------------- degree
__global__ __launch_bounds__(WG) void k_deg_init(int* __restrict__ deg, int n) {
    int i = blockIdx.x * WG + threadIdx.x;
    if (i < n) deg[i] = 1;  // self-loop
}

__global__ __launch_bounds__(WG) void k_deg_count(const int* __restrict__ dst,
                                                  int* __restrict__ deg, int e) {
    int i = blockIdx.x * WG + threadIdx.x;
    if (i < e) atomicAdd(&deg[dst[i]], 1);
}

// ------------------------------------------------ CSR build: 3-step scan
__global__ __launch_bounds__(WG) void k_scan1(const int* __restrict__ deg,
                                              float* __restrict__ dinv,
                                              int* __restrict__ base,
                                              int* __restrict__ bsum, int n) {
    __shared__ int t[WG];
    int tid = threadIdx.x;
    int i = blockIdx.x * WG + tid;
    int d = (i < n) ? deg[i] : 1;
    if (i < n) dinv[i] = rsqrtf((float)d);
    int v = (i < n) ? d - 1 : 0;
    t[tid] = v;
    __syncthreads();
    for (int o = 1; o < WG; o <<= 1) {
        int add = (tid >= o) ? t[tid - o] : 0;
        __syncthreads();
        t[tid] += add;
        __syncthreads();
    }
    if (i < n) base[i] = t[tid] - v;  // block-local exclusive
    if (tid == WG - 1) bsum[blockIdx.x] = t[WG - 1];
}

__global__ __launch_bounds__(WG) void k_scan2(int* __restrict__ bsum, int nb) {
    __shared__ int t[WG];
    int tid = threadIdx.x;
    int v = (tid < nb) ? bsum[tid] : 0;
    t[tid] = v;
    __syncthreads();
    for (int o = 1; o < WG; o <<= 1) {
        int add = (tid >= o) ? t[tid - o] : 0;
        __syncthreads();
        t[tid] += add;
        __syncthreads();
    }
    if (tid < nb) bsum[tid] = t[tid] - v;  // exclusive block offsets
}

__global__ __launch_bounds__(WG) void k_scan3(int* __restrict__ base,
                                              const int* __restrict__ bsum,
                                              int* __restrict__ cursor, int n, int e) {
    int i = blockIdx.x * WG + threadIdx.x;
    if (i < n) {
        int b = base[i] + bsum[blockIdx.x];
        base[i] = b;
        cursor[i] = b;
        if (i == n - 1) base[n] = e;
    }
}

__global__ __launch_bounds__(WG) void k_fill(const int* __restrict__ src,
                                             const int* __restrict__ dst,
                                             const float* __restrict__ dinv,
                                             int* __restrict__ cursor,
                                             int* __restrict__ esrc,
                                             float* __restrict__ ew, int e) {
    int i = blockIdx.x * WG + threadIdx.x;
    if (i >= e) return;
    int s = src[i], d = dst[i];
    int pos = atomicAdd(&cursor[d], 1);
    esrc[pos] = s;
    ew[pos] = dinv[s] * dinv[d];
}

// ---------- dst[n][k] = (f16) src[k][n]; K = 1<<logk, Nn = 128
__global__ __launch_bounds__(WG) void k_transpose(const float* __restrict__ src,
                                                  f16* __restrict__ dst, int logk) {
    int i = blockIdx.x * WG + threadIdx.x;  // i = n*K + k
    int K = 1 << logk;
    int k = i & (K - 1), nI = i >> logk;
    dst[i] = (f16)src[(size_t)k * 128 + nI];
}

// ---------- MFMA GEMM: Out[r][c] packed half2(c, c+64) of A[n,128] @ W (Wt = W^T f16)
// 64 rows/block, 4 waves * 16 rows. mfma_f32_16x16x32_f16.
__global__ __launch_bounds__(WG) void k_mm_hpk(const float* __restrict__ A,
                                               const f16* __restrict__ Wt,  // [128][128]
                                               __half2* __restrict__ Out, int n) {
    __shared__ f16 As[64][136];
    __shared__ f16 Bs[128][136];
    const int tid = threadIdx.x;
    const int row0 = blockIdx.x * 64;
    for (int f = tid; f < 128 * 16; f += WG) {  // Bs: 16B chunks
        int r = f >> 4, c = f & 15;
        *(float4*)&Bs[r][c * 8] = ((const float4*)Wt)[r * 16 + c];
    }
    for (int f = tid; f < 64 * 32; f += WG) {   // As: fp32->f16, 4 elems/chunk
        int r = f >> 5, c = f & 31;
        float4 v = make_float4(0.f, 0.f, 0.f, 0.f);
        if (row0 + r < n) v = ((const float4*)A)[(size_t)(row0 + r) * 32 + c];
        *(f16x4*)&As[r][c * 4] = (f16x4){(f16)v.x, (f16)v.y, (f16)v.z, (f16)v.w};
    }
    __syncthreads();
    const int wv = tid >> 6, lane = tid & 63, m = lane & 15, quad = lane >> 4;
    f32x4 acc[8];
#pragma unroll
    for (int t = 0; t < 8; ++t) acc[t] = (f32x4){0.f, 0.f, 0.f, 0.f};
#pragma unroll
    for (int kk = 0; kk < 4; ++kk) {
        f16x8 af = *(f16x8*)&As[wv * 16 + m][kk * 32 + quad * 8];
#pragma unroll
        for (int t = 0; t < 8; ++t) {
            f16x8 bf = *(f16x8*)&Bs[t * 16 + m][kk * 32 + quad * 8];
            acc[t] = __builtin_amdgcn_mfma_f32_16x16x32_f16(af, bf, acc[t], 0, 0, 0);
        }
    }
#pragma unroll
    for (int t = 0; t < 4; ++t)
#pragma unroll
        for (int r = 0; r < 4; ++r) {
            int row = row0 + wv * 16 + quad * 4 + r;
            if (row < n)
                Out[(size_t)row * 64 + t * 16 + m] = __floats2half2_rn(acc[t][r], acc[t + 4][r]);
        }
}

// ---------- Fused U/V MFMA GEMM: U = A@W1a + b1, V = A@W1b; packed (c, c+64)
// W1t = [128][256] f16 with W1t[j][k] = W1[k][j]; phase0 k<128, phase1 k>=128.
__global__ __launch_bounds__(WG) void k_mm_uv(const float* __restrict__ A,
                                              const f16* __restrict__ W1t,
                                              const float* __restrict__ b1,
                                              __half2* __restrict__ Up,
                                              __half2* __restrict__ Vp, int n) {
    __shared__ f16 As[64][136];
    __shared__ f16 Bs[128][136];
    const int tid = threadIdx.x;
    const int row0 = blockIdx.x * 64;
    for (int f = tid; f < 64 * 32; f += WG) {
        int r = f >> 5, c = f & 31;
        float4 v = make_float4(0.f, 0.f, 0.f, 0.f);
        if (row0 + r < n) v = ((const float4*)A)[(size_t)(row0 + r) * 32 + c];
        *(f16x4*)&As[r][c * 4] = (f16x4){(f16)v.x, (f16)v.y, (f16)v.z, (f16)v.w};
    }
    const int wv = tid >> 6, lane = tid & 63, m = lane & 15, quad = lane >> 4;
    f32x4 acc[8];
#pragma unroll
    for (int ph = 0; ph < 2; ++ph) {
        // stage Bs = rows of W1t, column block [ph*128, ph*128+128)
        if (ph) __syncthreads();  // prior compute done before overwrite
        for (int f = tid; f < 128 * 16; f += WG) {
            int r = f >> 4, c = f & 15;
            *(float4*)&Bs[r][c * 8] = *(const float4*)(W1t + (size_t)r * 256 + ph * 128 + c * 8);
        }
        __syncthreads();
#pragma unroll
        for (int t = 0; t < 8; ++t) acc[t] = (f32x4){0.f, 0.f, 0.f, 0.f};
#pragma unroll
        for (int kk = 0; kk < 4; ++kk) {
            f16x8 af = *(f16x8*)&As[wv * 16 + m][kk * 32 + quad * 8];
#pragma unroll
            for (int t = 0; t < 8; ++t) {
                f16x8 bf = *(f16x8*)&Bs[t * 16 + m][kk * 32 + quad * 8];
                acc[t] = __builtin_amdgcn_mfma_f32_16x16x32_f16(af, bf, acc[t], 0, 0, 0);
            }
        }
        __half2* Out = ph ? Vp : Up;
#pragma unroll
        for (int t = 0; t < 4; ++t) {
            float bl = 0.f, bh = 0.f;
            if (!ph) { bl = b1[t * 16 + m]; bh = b1[t * 16 + m + 64]; }
#pragma unroll
            for (int r = 0; r < 4; ++r) {
                int row = row0 + wv * 16 + quad * 4 + r;
                if (row < n)
                    Out[(size_t)row * 64 + t * 16 + m] =
                        __floats2half2_rn(acc[t][r] + bl, acc[t + 4][r] + bh);
            }
        }
    }
}

// ------------- gather: out_h[d] = h0[d]*dinv[d]^2 + b + sum_in h0[s]*w
// Hpk packed (col lane, col lane+64). One wave64/node, x4 unroll.
__global__ __launch_bounds__(WG) void k_gather(const __half2* __restrict__ Hpk,
                                               const float* __restrict__ dinv,
                                               const float* __restrict__ bg,
                                               const int* __restrict__ base,
                                               const int* __restrict__ esrc,
                                               const float* __restrict__ ew,
                                               float* __restrict__ outh, int n) {
    int node = blockIdx.x * 4 + (threadIdx.x >> 6);
    int lane = threadIdx.x & 63;
    if (node >= n) return;
    float dv = dinv[node];
    float s2 = dv * dv;
    float bl = bg[lane], bh = bg[lane + 64];
    __half2 hs = Hpk[(size_t)node * 64 + lane];
    float2 acc = make_float2(fmaf(__low2float(hs), s2, bl),
                             fmaf(__high2float(hs), s2, bh));
    int j = base[node], jend = base[node + 1];
    for (; j + 4 <= jend; j += 4) {
        int i0 = esrc[j], i1 = esrc[j + 1], i2 = esrc[j + 2], i3 = esrc[j + 3];
        float w0 = ew[j], w1 = ew[j + 1], w2 = ew[j + 2], w3 = ew[j + 3];
        __half2 v0 = Hpk[(size_t)i0 * 64 + lane];
        __half2 v1 = Hpk[(size_t)i1 * 64 + lane];
        __half2 v2 = Hpk[(size_t)i2 * 64 + lane];
        __half2 v3 = Hpk[(size_t)i3 * 64 + lane];
        acc.x = fmaf(__low2float(v0), w0, acc.x); acc.y = fmaf(__high2float(v0), w0, acc.y);
        acc.x = fmaf(__low2float(v1), w1, acc.x); acc.y = fmaf(__high2float(v1), w1, acc.y);
        acc.x = fmaf(__low2float(v2), w2, acc.x); acc.y = fmaf(__high2float(v2), w2, acc.y);
        acc.x = fmaf(__low2float(v3), w3, acc.x); acc.y = fmaf(__high2float(v3), w3, acc.y);
    }
    for (; j < jend; ++j) {
        int s = esrc[j];
        float w = ew[j];
        __half2 v = Hpk[(size_t)s * 64 + lane];
        acc.x = fmaf(__low2float(v), w, acc.x);
        acc.y = fmaf(__high2float(v), w, acc.y);
    }
    outh[(size_t)node * 128 + lane] = acc.x;
    outh[(size_t)node * 128 + 64 + lane] = acc.y;
}

// --------- 1 pair per 16 lanes: logit = relu(U[a]+V[b]).W2 + b2 (b1 in U)
__global__ __launch_bounds__(WG) void k_pair16(const __half2* __restrict__ U,
                                               const __half2* __restrict__ V,
                                               const float* __restrict__ W2,
                                               const float* __restrict__ b2,
                                               const int* __restrict__ pairs,
                                               float* __restrict__ out_logit, int p) {
    int wv = (blockIdx.x * WG + threadIdx.x) >> 6;
    int lane = threadIdx.x & 63;
    int g = lane >> 4, sub = lane & 15;
    int q = wv * 4 + g;
    bool valid = (q < p);
    int qa = valid ? q : 0;
    int a = pairs[2 * qa], b = pairs[2 * qa + 1];

    float4 w2lo = ((const float4*)W2)[sub];
    float4 w2hi = ((const float4*)(W2 + 64))[sub];
    hv2 w2h[4];
    w2h[0] = hv2{(f16)w2lo.x, (f16)w2hi.x};
    w2h[1] = hv2{(f16)w2lo.y, (f16)w2hi.y};
    w2h[2] = hv2{(f16)w2lo.z, (f16)w2hi.z};
    w2h[3] = hv2{(f16)w2lo.w, (f16)w2hi.w};

    int4 uu = *(const int4*)(U + (size_t)a * 64 + 4 * sub);
    int4 vv = *(const int4*)(V + (size_t)b * 64 + 4 * sub);
    const int* ui = (const int*)&uu;
    const int* vi = (const int*)&vv;

    float part = 0.f;
#pragma unroll
    for (int k = 0; k < 4; ++k) {
        hv2 s = __builtin_bit_cast(hv2, ui[k]) + __builtin_bit_cast(hv2, vi[k]);
        hv2 z = __builtin_elementwise_max(s, hv2{(f16)0.f, (f16)0.f});
        part = __builtin_amdgcn_fdot2(z, w2h[k], part, false);
    }
#pragma unroll
    for (int m = 1; m < 16; m <<= 1) part += __shfl_xor(part, m, 64);
    if (sub == 0 && valid) out_logit[q] = part + b2[0];
}

// --------- out_pairs[i] = (float)pairs[i], vectorized
__global__ __launch_bounds__(WG) void k_cvtpairs(const int* __restrict__ pairs,
                                                 float* __restrict__ outp, int n4) {
    int i = blockIdx.x * WG + threadIdx.x;
    if (i >= n4) return;
    int4 v = ((const int4*)pairs)[i];
    ((float4*)outp)[i] = make_float4((float)v.x, (float)v.y, (float)v.z, (float)v.w);
}

extern "C" void kernel_launch(void* const* d_in, const int* in_sizes, int n_in,
                              void* d_out, int out_size, void* d_ws, size_t ws_size,
                              hipStream_t stream) {
    const float* x     = (const float*)d_in[0];
    const int*   eidx  = (const int*)d_in[1];
    const int*   pairs = (const int*)d_in[2];
    const float* W_gcn = (const float*)d_in[3];
    const float* b_gcn = (const float*)d_in[4];
    const float* W1    = (const float*)d_in[5];
    const float* b1    = (const float*)d_in[6];
    const float* W2    = (const float*)d_in[7];
    const float* b2    = (const float*)d_in[8];

    const int N = in_sizes[0] / 128;
    const int E = in_sizes[1] / 2;
    const int P = in_sizes[2] / 2;
    const int* esrc_in = eidx;
    const int* edst_in = eidx + E;

    // workspace layout (4-byte units)
    float* ws      = (float*)d_ws;
    int*   deg     = (int*)d_ws;                  // [N]
    float* dinv    = ws + 65536;                  // [N]
    int*   base    = (int*)(ws + 131072);         // [N+1]
    int*   cursor  = (int*)(ws + 196608);         // [N]
    int*   bsum    = (int*)(ws + 262144);         // [256]
    f16*   Wt_gcn  = (f16*)(ws + 262400);         // [128*128] f16 = 8192 floats
    f16*   W1t     = (f16*)(ws + 270592);         // [128*256] f16 = 16384 floats
    int*   ecsr    = (int*)(ws + 287744);         // [E]
    float* ew      = ws + 287744 + E;             // [E]
    __half2* Hpk   = (__half2*)(ws + 287744 + 2 * (size_t)E);  // [N*64]
    __half2* Upk   = Hpk + (size_t)N * 64;        // [N*64]
    __half2* Vpk   = Upk + (size_t)N * 64;        // [N*64]

    float* out_logit = (float*)d_out;             // [P]
    float* out_pairs = out_logit + P;             // [2P] as float
    float* out_h     = out_logit + 3 * (size_t)P; // [N*128]

    const int nb = (N + WG - 1) / WG;  // 196 <= 256
    dim3 blk(WG);
    dim3 grid_pair((unsigned)((P + 15) / 16));
    k_deg_init  <<<nb, blk, 0, stream>>>(deg, N);
    k_deg_count <<<(E + WG - 1) / WG, blk, 0, stream>>>(edst_in, deg, E);
    k_scan1     <<<nb, blk, 0, stream>>>(deg, dinv, base, bsum, N);
    k_scan2     <<<1,  blk, 0, stream>>>(bsum, nb);
    k_scan3     <<<nb, blk, 0, stream>>>(base, bsum, cursor, N, E);
    k_fill      <<<(E + WG - 1) / WG, blk, 0, stream>>>(esrc_in, edst_in, dinv, cursor, ecsr, ew, E);
    k_transpose <<<(128 * 128) / WG, blk, 0, stream>>>(W_gcn, Wt_gcn, 7);
    k_transpose <<<(128 * 256) / WG, blk, 0, stream>>>(W1, W1t, 8);
    k_mm_hpk    <<<(N + 63) / 64, blk, 0, stream>>>(x, Wt_gcn, Hpk, N);
    k_gather    <<<(N + 3) / 4, blk, 0, stream>>>(Hpk, dinv, b_gcn, base, ecsr, ew, out_h, N);
    k_mm_uv     <<<(N + 63) / 64, blk, 0, stream>>>(out_h, W1t, b1, Upk, Vpk, N);
    k_cvtpairs  <<<(P / 2 + WG - 1) / WG, blk, 0, stream>>>(pairs, out_pairs, P / 2);
    k_pair16    <<<grid_pair, blk, 0, stream>>>(Upk, Vpk, W2, b2, pairs, out_logit, P);
}

// Round 8
// 324.848 us; speedup vs baseline: 2.3943x; 1.0004x over previous
//
#include <hip/hip_runtime.h>
#include <hip/hip_fp16.h>

#define WG 256

typedef _Float16 f16;
typedef _Float16 hv2 __attribute__((ext_vector_type(2)));
typedef _Float16 f16x4 __attribute__((ext_vector_type(4)));
typedef _Float16 f16x8 __attribute__((ext_vector_type(8)));
typedef float f32x4 __attribute__((ext_vector_type(4)));

// ---------------------------------------------------------------- degree
__global__ __launch_bounds__(WG) void k_deg_init(int* __restrict__ deg, int n) {
    int i = blockIdx.x * WG + threadIdx.x;
    if (i < n) deg[i] = 1;  // self-loop
}

__global__ __launch_bounds__(WG) void k_deg_count(const int* __restrict__ dst,
                                                  int* __restrict__ deg, int e) {
    int i = blockIdx.x * WG + threadIdx.x;
    if (i < e) atomicAdd(&deg[dst[i]], 1);
}

// ------------------------------------------------ CSR build: 3-step scan
__global__ __launch_bounds__(WG) void k_scan1(const int* __restrict__ deg,
                                              float* __restrict__ dinv,
                                              int* __restrict__ base,
                                              int* __restrict__ bsum, int n) {
    __shared__ int t[WG];
    int tid = threadIdx.x;
    int i = blockIdx.x * WG + tid;
    int d = (i < n) ? deg[i] : 1;
    if (i < n) dinv[i] = rsqrtf((float)d);
    int v = (i < n) ? d - 1 : 0;
    t[tid] = v;
    __syncthreads();
    for (int o = 1; o < WG; o <<= 1) {
        int add = (tid >= o) ? t[tid - o] : 0;
        __syncthreads();
        t[tid] += add;
        __syncthreads();
    }
    if (i < n) base[i] = t[tid] - v;  // block-local exclusive
    if (tid == WG - 1) bsum[blockIdx.x] = t[WG - 1];
}

__global__ __launch_bounds__(WG) void k_scan2(int* __restrict__ bsum, int nb) {
    __shared__ int t[WG];
    int tid = threadIdx.x;
    int v = (tid < nb) ? bsum[tid] : 0;
    t[tid] = v;
    __syncthreads();
    for (int o = 1; o < WG; o <<= 1) {
        int add = (tid >= o) ? t[tid - o] : 0;
        __syncthreads();
        t[tid] += add;
        __syncthreads();
    }
    if (tid < nb) bsum[tid] = t[tid] - v;  // exclusive block offsets
}

__global__ __launch_bounds__(WG) void k_scan3(int* __restrict__ base,
                                              const int* __restrict__ bsum,
                                              int* __restrict__ cursor, int n, int e) {
    int i = blockIdx.x * WG + threadIdx.x;
    if (i < n) {
        int b = base[i] + bsum[blockIdx.x];
        base[i] = b;
        cursor[i] = b;
        if (i == n - 1) base[n] = e;
    }
}

__global__ __launch_bounds__(WG) void k_fill(const int* __restrict__ src,
                                             const int* __restrict__ dst,
                                             const float* __restrict__ dinv,
                                             int* __restrict__ cursor,
                                             int* __restrict__ esrc,
                                             float* __restrict__ ew, int e) {
    int i = blockIdx.x * WG + threadIdx.x;
    if (i >= e) return;
    int s = src[i], d = dst[i];
    int pos = atomicAdd(&cursor[d], 1);
    esrc[pos] = s;
    ew[pos] = dinv[s] * dinv[d];
}

// ---------- dst[n][k] = (f16) src[k][n]; K = 1<<logk, Nn = 128
__global__ __launch_bounds__(WG) void k_transpose(const float* __restrict__ src,
                                                  f16* __restrict__ dst, int logk) {
    int i = blockIdx.x * WG + threadIdx.x;  // i = n*K + k
    int K = 1 << logk;
    int k = i & (K - 1), nI = i >> logk;
    dst[i] = (f16)src[(size_t)k * 128 + nI];
}

// ---------- MFMA GEMM: Out[r][c] packed half2(c, c+64) of A[n,128] @ W (Wt = W^T f16)
__global__ __launch_bounds__(WG) void k_mm_hpk(const float* __restrict__ A,
                                               const f16* __restrict__ Wt,  // [128][128]
                                               __half2* __restrict__ Out, int n) {
    __shared__ f16 As[64][136];
    __shared__ f16 Bs[128][136];
    const int tid = threadIdx.x;
    const int row0 = blockIdx.x * 64;
    for (int f = tid; f < 128 * 16; f += WG) {
        int r = f >> 4, c = f & 15;
        *(float4*)&Bs[r][c * 8] = ((const float4*)Wt)[r * 16 + c];
    }
    for (int f = tid; f < 64 * 32; f += WG) {
        int r = f >> 5, c = f & 31;
        float4 v = make_float4(0.f, 0.f, 0.f, 0.f);
        if (row0 + r < n) v = ((const float4*)A)[(size_t)(row0 + r) * 32 + c];
        *(f16x4*)&As[r][c * 4] = (f16x4){(f16)v.x, (f16)v.y, (f16)v.z, (f16)v.w};
    }
    __syncthreads();
    const int wv = tid >> 6, lane = tid & 63, m = lane & 15, quad = lane >> 4;
    f32x4 acc[8];
#pragma unroll
    for (int t = 0; t < 8; ++t) acc[t] = (f32x4){0.f, 0.f, 0.f, 0.f};
#pragma unroll
    for (int kk = 0; kk < 4; ++kk) {
        f16x8 af = *(f16x8*)&As[wv * 16 + m][kk * 32 + quad * 8];
#pragma unroll
        for (int t = 0; t < 8; ++t) {
            f16x8 bf = *(f16x8*)&Bs[t * 16 + m][kk * 32 + quad * 8];
            acc[t] = __builtin_amdgcn_mfma_f32_16x16x32_f16(af, bf, acc[t], 0, 0, 0);
        }
    }
#pragma unroll
    for (int t = 0; t < 4; ++t)
#pragma unroll
        for (int r = 0; r < 4; ++r) {
            int row = row0 + wv * 16 + quad * 4 + r;
            if (row < n)
                Out[(size_t)row * 64 + t * 16 + m] = __floats2half2_rn(acc[t][r], acc[t + 4][r]);
        }
}

// ---------- Fused U/V MFMA GEMM: U = A@W1a + b1, V = A@W1b; packed (c, c+64)
__global__ __launch_bounds__(WG) void k_mm_uv(const float* __restrict__ A,
                                              const f16* __restrict__ W1t,
                                              const float* __restrict__ b1,
                                              __half2* __restrict__ Up,
                                              __half2* __restrict__ Vp, int n) {
    __shared__ f16 As[64][136];
    __shared__ f16 Bs[128][136];
    const int tid = threadIdx.x;
    const int row0 = blockIdx.x * 64;
    for (int f = tid; f < 64 * 32; f += WG) {
        int r = f >> 5, c = f & 31;
        float4 v = make_float4(0.f, 0.f, 0.f, 0.f);
        if (row0 + r < n) v = ((const float4*)A)[(size_t)(row0 + r) * 32 + c];
        *(f16x4*)&As[r][c * 4] = (f16x4){(f16)v.x, (f16)v.y, (f16)v.z, (f16)v.w};
    }
    const int wv = tid >> 6, lane = tid & 63, m = lane & 15, quad = lane >> 4;
    f32x4 acc[8];
#pragma unroll
    for (int ph = 0; ph < 2; ++ph) {
        if (ph) __syncthreads();
        for (int f = tid; f < 128 * 16; f += WG) {
            int r = f >> 4, c = f & 15;
            *(float4*)&Bs[r][c * 8] = *(const float4*)(W1t + (size_t)r * 256 + ph * 128 + c * 8);
        }
        __syncthreads();
#pragma unroll
        for (int t = 0; t < 8; ++t) acc[t] = (f32x4){0.f, 0.f, 0.f, 0.f};
#pragma unroll
        for (int kk = 0; kk < 4; ++kk) {
            f16x8 af = *(f16x8*)&As[wv * 16 + m][kk * 32 + quad * 8];
#pragma unroll
            for (int t = 0; t < 8; ++t) {
                f16x8 bf = *(f16x8*)&Bs[t * 16 + m][kk * 32 + quad * 8];
                acc[t] = __builtin_amdgcn_mfma_f32_16x16x32_f16(af, bf, acc[t], 0, 0, 0);
            }
        }
        __half2* Out = ph ? Vp : Up;
#pragma unroll
        for (int t = 0; t < 4; ++t) {
            float bl = 0.f, bh = 0.f;
            if (!ph) { bl = b1[t * 16 + m]; bh = b1[t * 16 + m + 64]; }
#pragma unroll
            for (int r = 0; r < 4; ++r) {
                int row = row0 + wv * 16 + quad * 4 + r;
                if (row < n)
                    Out[(size_t)row * 64 + t * 16 + m] =
                        __floats2half2_rn(acc[t][r] + bl, acc[t + 4][r] + bh);
            }
        }
    }
}

// ------------- gather: 16 lanes/node, lane owns 8 cols (int4 of 4 half2).
// 4 nodes/wave, x4 edge unroll -> 16 row-gathers in flight per wave.
__global__ __launch_bounds__(WG) void k_gather(const __half2* __restrict__ Hpk,
                                               const float* __restrict__ dinv,
                                               const float* __restrict__ bg,
                                               const int* __restrict__ base,
                                               const int* __restrict__ esrc,
                                               const float* __restrict__ ew,
                                               float* __restrict__ outh, int n) {
    int tid = threadIdx.x;
    int node = blockIdx.x * 16 + (tid >> 4);
    int sub = tid & 15;
    if (node >= n) return;
    float dv = dinv[node];
    float s2 = dv * dv;
    float4 blo = *(const float4*)(bg + 4 * sub);
    float4 bhi = *(const float4*)(bg + 4 * sub + 64);
    int4 hh = *(const int4*)(Hpk + (size_t)node * 64 + 4 * sub);
    const int* hp = (const int*)&hh;
    float accl[4], acch[4];
#pragma unroll
    for (int k = 0; k < 4; ++k) {
        hv2 h = __builtin_bit_cast(hv2, hp[k]);
        accl[k] = fmaf((float)h[0], s2, ((const float*)&blo)[k]);
        acch[k] = fmaf((float)h[1], s2, ((const float*)&bhi)[k]);
    }
    int j = base[node], jend = base[node + 1];
    for (; j + 4 <= jend; j += 4) {
        int s0 = esrc[j], s1 = esrc[j + 1], s2i = esrc[j + 2], s3 = esrc[j + 3];
        float w0 = ew[j], w1 = ew[j + 1], w2 = ew[j + 2], w3 = ew[j + 3];
        int4 r0 = *(const int4*)(Hpk + (size_t)s0 * 64 + 4 * sub);
        int4 r1 = *(const int4*)(Hpk + (size_t)s1 * 64 + 4 * sub);
        int4 r2 = *(const int4*)(Hpk + (size_t)s2i * 64 + 4 * sub);
        int4 r3 = *(const int4*)(Hpk + (size_t)s3 * 64 + 4 * sub);
        const int* p0 = (const int*)&r0;
        const int* p1 = (const int*)&r1;
        const int* p2 = (const int*)&r2;
        const int* p3 = (const int*)&r3;
#pragma unroll
        for (int k = 0; k < 4; ++k) {
            hv2 h0 = __builtin_bit_cast(hv2, p0[k]);
            hv2 h1 = __builtin_bit_cast(hv2, p1[k]);
            hv2 h2 = __builtin_bit_cast(hv2, p2[k]);
            hv2 h3 = __builtin_bit_cast(hv2, p3[k]);
            accl[k] = fmaf((float)h0[0], w0, accl[k]); acch[k] = fmaf((float)h0[1], w0, acch[k]);
            accl[k] = fmaf((float)h1[0], w1, accl[k]); acch[k] = fmaf((float)h1[1], w1, acch[k]);
            accl[k] = fmaf((float)h2[0], w2, accl[k]); acch[k] = fmaf((float)h2[1], w2, acch[k]);
            accl[k] = fmaf((float)h3[0], w3, accl[k]); acch[k] = fmaf((float)h3[1], w3, acch[k]);
        }
    }
    for (; j < jend; ++j) {
        int s = esrc[j];
        float w = ew[j];
        int4 r = *(const int4*)(Hpk + (size_t)s * 64 + 4 * sub);
        const int* pr = (const int*)&r;
#pragma unroll
        for (int k = 0; k < 4; ++k) {
            hv2 h = __builtin_bit_cast(hv2, pr[k]);
            accl[k] = fmaf((float)h[0], w, accl[k]);
            acch[k] = fmaf((float)h[1], w, acch[k]);
        }
    }
    *(float4*)&outh[(size_t)node * 128 + 4 * sub] =
        make_float4(accl[0], accl[1], accl[2], accl[3]);
    *(float4*)&outh[(size_t)node * 128 + 64 + 4 * sub] =
        make_float4(acch[0], acch[1], acch[2], acch[3]);
}

// --------- 2 pairs per 16-lane group (8/wave): logit = relu(U[a]+V[b]).W2 + b2
__global__ __launch_bounds__(WG) void k_pair8(const __half2* __restrict__ U,
                                              const __half2* __restrict__ V,
                                              const float* __restrict__ W2,
                                              const float* __restrict__ b2,
                                              const int* __restrict__ pairs,
                                              float* __restrict__ out_logit, int p) {
    int wv = (blockIdx.x * WG + threadIdx.x) >> 6;
    int lane = threadIdx.x & 63;
    int g = lane >> 4, sub = lane & 15;
    int q0 = wv * 8 + g, q1 = q0 + 4;
    bool v0 = (q0 < p), v1 = (q1 < p);
    if (!v0) return;
    int qa0 = q0, qa1 = v1 ? q1 : q0;
    int a0 = pairs[2 * qa0], b0 = pairs[2 * qa0 + 1];
    int a1 = pairs[2 * qa1], b1i = pairs[2 * qa1 + 1];

    float4 w2lo = ((const float4*)W2)[sub];
    float4 w2hi = ((const float4*)(W2 + 64))[sub];
    hv2 w2h[4];
    w2h[0] = hv2{(f16)w2lo.x, (f16)w2hi.x};
    w2h[1] = hv2{(f16)w2lo.y, (f16)w2hi.y};
    w2h[2] = hv2{(f16)w2lo.z, (f16)w2hi.z};
    w2h[3] = hv2{(f16)w2lo.w, (f16)w2hi.w};

    int4 u0 = *(const int4*)(U + (size_t)a0 * 64 + 4 * sub);
    int4 vv0 = *(const int4*)(V + (size_t)b0 * 64 + 4 * sub);
    int4 u1 = *(const int4*)(U + (size_t)a1 * 64 + 4 * sub);
    int4 vv1 = *(const int4*)(V + (size_t)b1i * 64 + 4 * sub);
    const int* ui0 = (const int*)&u0;
    const int* vi0 = (const int*)&vv0;
    const int* ui1 = (const int*)&u1;
    const int* vi1 = (const int*)&vv1;

    const hv2 z2 = hv2{(f16)0.f, (f16)0.f};
    float p0 = 0.f, p1 = 0.f;
#pragma unroll
    for (int k = 0; k < 4; ++k) {
        hv2 s0 = __builtin_bit_cast(hv2, ui0[k]) + __builtin_bit_cast(hv2, vi0[k]);
        hv2 s1 = __builtin_bit_cast(hv2, ui1[k]) + __builtin_bit_cast(hv2, vi1[k]);
        p0 = __builtin_amdgcn_fdot2(__builtin_elementwise_max(s0, z2), w2h[k], p0, false);
        p1 = __builtin_amdgcn_fdot2(__builtin_elementwise_max(s1, z2), w2h[k], p1, false);
    }
#pragma unroll
    for (int m = 1; m < 16; m <<= 1) {
        p0 += __shfl_xor(p0, m, 64);
        p1 += __shfl_xor(p1, m, 64);
    }
    if (sub == 0) {
        float bb = b2[0];
        out_logit[q0] = p0 + bb;
        if (v1) out_logit[q1] = p1 + bb;
    }
}

// --------- out_pairs[i] = (float)pairs[i], vectorized
__global__ __launch_bounds__(WG) void k_cvtpairs(const int* __restrict__ pairs,
                                                 float* __restrict__ outp, int n4) {
    int i = blockIdx.x * WG + threadIdx.x;
    if (i >= n4) return;
    int4 v = ((const int4*)pairs)[i];
    ((float4*)outp)[i] = make_float4((float)v.x, (float)v.y, (float)v.z, (float)v.w);
}

extern "C" void kernel_launch(void* const* d_in, const int* in_sizes, int n_in,
                              void* d_out, int out_size, void* d_ws, size_t ws_size,
                              hipStream_t stream) {
    const float* x     = (const float*)d_in[0];
    const int*   eidx  = (const int*)d_in[1];
    const int*   pairs = (const int*)d_in[2];
    const float* W_gcn = (const float*)d_in[3];
    const float* b_gcn = (const float*)d_in[4];
    const float* W1    = (const float*)d_in[5];
    const float* b1    = (const float*)d_in[6];
    const float* W2    = (const float*)d_in[7];
    const float* b2    = (const float*)d_in[8];

    const int N = in_sizes[0] / 128;
    const int E = in_sizes[1] / 2;
    const int P = in_sizes[2] / 2;
    const int* esrc_in = eidx;
    const int* edst_in = eidx + E;

    // workspace layout (4-byte units)
    float* ws      = (float*)d_ws;
    int*   deg     = (int*)d_ws;                  // [N]
    float* dinv    = ws + 65536;                  // [N]
    int*   base    = (int*)(ws + 131072);         // [N+1]
    int*   cursor  = (int*)(ws + 196608);         // [N]
    int*   bsum    = (int*)(ws + 262144);         // [256]
    f16*   Wt_gcn  = (f16*)(ws + 262400);         // [128*128] f16
    f16*   W1t     = (f16*)(ws + 270592);         // [128*256] f16
    int*   ecsr    = (int*)(ws + 287744);         // [E]
    float* ew      = ws + 287744 + E;             // [E]
    __half2* Hpk   = (__half2*)(ws + 287744 + 2 * (size_t)E);  // [N*64]
    __half2* Upk   = Hpk + (size_t)N * 64;        // [N*64]
    __half2* Vpk   = Upk + (size_t)N * 64;        // [N*64]

    float* out_logit = (float*)d_out;             // [P]
    float* out_pairs = out_logit + P;             // [2P] as float
    float* out_h     = out_logit + 3 * (size_t)P; // [N*128]

    const int nb = (N + WG - 1) / WG;  // 196 <= 256
    dim3 blk(WG);
    dim3 grid_pair((unsigned)((P + 31) / 32));
    k_deg_init  <<<nb, blk, 0, stream>>>(deg, N);
    k_deg_count <<<(E + WG - 1) / WG, blk, 0, stream>>>(edst_in, deg, E);
    k_scan1     <<<nb, blk, 0, stream>>>(deg, dinv, base, bsum, N);
    k_scan2     <<<1,  blk, 0, stream>>>(bsum, nb);
    k_scan3     <<<nb, blk, 0, stream>>>(base, bsum, cursor, N, E);
    k_fill      <<<(E + WG - 1) / WG, blk, 0, stream>>>(esrc_in, edst_in, dinv, cursor, ecsr, ew, E);
    k_transpose <<<(128 * 128) / WG, blk, 0, stream>>>(W_gcn, Wt_gcn, 7);
    k_transpose <<<(128 * 256) / WG, blk, 0, stream>>>(W1, W1t, 8);
    k_mm_hpk    <<<(N + 63) / 64, blk, 0, stream>>>(x, Wt_gcn, Hpk, N);
    k_gather    <<<(N + 15) / 16, blk, 0, stream>>>(Hpk, dinv, b_gcn, base, ecsr, ew, out_h, N);
    k_mm_uv     <<<(N + 63) / 64, blk, 0, stream>>>(out_h, W1t, b1, Upk, Vpk, N);
    k_cvtpairs  <<<(P / 2 + WG - 1) / WG, blk, 0, stream>>>(pairs, out_pairs, P / 2);
    k_pair8     <<<grid_pair, blk, 0, stream>>>(Upk, Vpk, W2, b2, pairs, out_logit, P);
}

// Round 9
// 316.336 us; speedup vs baseline: 2.4588x; 1.0269x over previous
//
#include <hip/hip_runtime.h>
#include <hip/hip_fp16.h>

#define WG 256

typedef _Float16 f16;
typedef _Float16 hv2 __attribute__((ext_vector_type(2)));
typedef _Float16 f16x4 __attribute__((ext_vector_type(4)));
typedef _Float16 f16x8 __attribute__((ext_vector_type(8)));
typedef float f32x4 __attribute__((ext_vector_type(4)));

// ---------------------------------------------------------------- degree
__global__ __launch_bounds__(WG) void k_deg_count(const int* __restrict__ dst,
                                                  int* __restrict__ deg, int e) {
    int i = blockIdx.x * WG + threadIdx.x;
    if (i < e) atomicAdd(&deg[dst[i]], 1);
}

// ------------------------------------------------ CSR build: 3-step scan
// deg[] holds pure in-degree (self-loop handled via +1 here).
__global__ __launch_bounds__(WG) void k_scan1(const int* __restrict__ deg,
                                              float* __restrict__ dinv,
                                              int* __restrict__ base,
                                              int* __restrict__ bsum, int n) {
    __shared__ int t[WG];
    int tid = threadIdx.x;
    int i = blockIdx.x * WG + tid;
    int v = (i < n) ? deg[i] : 0;
    if (i < n) dinv[i] = rsqrtf((float)(v + 1));
    t[tid] = v;
    __syncthreads();
    for (int o = 1; o < WG; o <<= 1) {
        int add = (tid >= o) ? t[tid - o] : 0;
        __syncthreads();
        t[tid] += add;
        __syncthreads();
    }
    if (i < n) base[i] = t[tid] - v;  // block-local exclusive
    if (tid == WG - 1) bsum[blockIdx.x] = t[WG - 1];
}

__global__ __launch_bounds__(WG) void k_scan2(int* __restrict__ bsum, int nb) {
    __shared__ int t[WG];
    int tid = threadIdx.x;
    int v = (tid < nb) ? bsum[tid] : 0;
    t[tid] = v;
    __syncthreads();
    for (int o = 1; o < WG; o <<= 1) {
        int add = (tid >= o) ? t[tid - o] : 0;
        __syncthreads();
        t[tid] += add;
        __syncthreads();
    }
    if (tid < nb) bsum[tid] = t[tid] - v;  // exclusive block offsets
}

__global__ __launch_bounds__(WG) void k_scan3(int* __restrict__ base,
                                              const int* __restrict__ bsum,
                                              int* __restrict__ cursor, int n, int e) {
    int i = blockIdx.x * WG + threadIdx.x;
    if (i < n) {
        int b = base[i] + bsum[blockIdx.x];
        base[i] = b;
        cursor[i] = b;
        if (i == n - 1) base[n] = e;
    }
}

// ---------------- fill: esrc only (edge weight folded into Hpk + dinv[d])
__global__ __launch_bounds__(WG) void k_fill(const int* __restrict__ src,
                                             const int* __restrict__ dst,
                                             int* __restrict__ cursor,
                                             int* __restrict__ esrc, int e) {
    int i = blockIdx.x * WG + threadIdx.x;
    if (i >= e) return;
    int s = src[i], d = dst[i];
    int pos = atomicAdd(&cursor[d], 1);
    esrc[pos] = s;
}

// ---------- dst[n][k] = (f16) src[k][n]; K = 1<<logk, Nn = 128
__global__ __launch_bounds__(WG) void k_transpose(const float* __restrict__ src,
                                                  f16* __restrict__ dst, int logk) {
    int i = blockIdx.x * WG + threadIdx.x;  // i = n*K + k
    int K = 1 << logk;
    int k = i & (K - 1), nI = i >> logk;
    dst[i] = (f16)src[(size_t)k * 128 + nI];
}

// ---------- MFMA GEMM: Hpk'[r][c] = half2 of (A@W)[r][{c,c+64}] * dinv[r]
__global__ __launch_bounds__(WG) void k_mm_hpk(const float* __restrict__ A,
                                               const f16* __restrict__ Wt,  // [128][128]
                                               const float* __restrict__ dinv,
                                               __half2* __restrict__ Out, int n) {
    __shared__ f16 As[64][136];
    __shared__ f16 Bs[128][136];
    const int tid = threadIdx.x;
    const int row0 = blockIdx.x * 64;
    for (int f = tid; f < 128 * 16; f += WG) {
        int r = f >> 4, c = f & 15;
        *(float4*)&Bs[r][c * 8] = ((const float4*)Wt)[r * 16 + c];
    }
    for (int f = tid; f < 64 * 32; f += WG) {
        int r = f >> 5, c = f & 31;
        float4 v = make_float4(0.f, 0.f, 0.f, 0.f);
        if (row0 + r < n) v = ((const float4*)A)[(size_t)(row0 + r) * 32 + c];
        *(f16x4*)&As[r][c * 4] = (f16x4){(f16)v.x, (f16)v.y, (f16)v.z, (f16)v.w};
    }
    __syncthreads();
    const int wv = tid >> 6, lane = tid & 63, m = lane & 15, quad = lane >> 4;
    f32x4 acc[8];
#pragma unroll
    for (int t = 0; t < 8; ++t) acc[t] = (f32x4){0.f, 0.f, 0.f, 0.f};
#pragma unroll
    for (int kk = 0; kk < 4; ++kk) {
        f16x8 af = *(f16x8*)&As[wv * 16 + m][kk * 32 + quad * 8];
#pragma unroll
        for (int t = 0; t < 8; ++t) {
            f16x8 bf = *(f16x8*)&Bs[t * 16 + m][kk * 32 + quad * 8];
            acc[t] = __builtin_amdgcn_mfma_f32_16x16x32_f16(af, bf, acc[t], 0, 0, 0);
        }
    }
#pragma unroll
    for (int r = 0; r < 4; ++r) {
        int row = row0 + wv * 16 + quad * 4 + r;
        if (row < n) {
            float dv = dinv[row];
#pragma unroll
            for (int t = 0; t < 4; ++t)
                Out[(size_t)row * 64 + t * 16 + m] =
                    __floats2half2_rn(acc[t][r] * dv, acc[t + 4][r] * dv);
        }
    }
}

// ---------- Fused U/V MFMA GEMM: U = A@W1a + b1, V = A@W1b; packed (c, c+64)
__global__ __launch_bounds__(WG) void k_mm_uv(const float* __restrict__ A,
                                              const f16* __restrict__ W1t,
                                              const float* __restrict__ b1,
                                              __half2* __restrict__ Up,
                                              __half2* __restrict__ Vp, int n) {
    __shared__ f16 As[64][136];
    __shared__ f16 Bs[128][136];
    const int tid = threadIdx.x;
    const int row0 = blockIdx.x * 64;
    for (int f = tid; f < 64 * 32; f += WG) {
        int r = f >> 5, c = f & 31;
        float4 v = make_float4(0.f, 0.f, 0.f, 0.f);
        if (row0 + r < n) v = ((const float4*)A)[(size_t)(row0 + r) * 32 + c];
        *(f16x4*)&As[r][c * 4] = (f16x4){(f16)v.x, (f16)v.y, (f16)v.z, (f16)v.w};
    }
    const int wv = tid >> 6, lane = tid & 63, m = lane & 15, quad = lane >> 4;
    f32x4 acc[8];
#pragma unroll
    for (int ph = 0; ph < 2; ++ph) {
        if (ph) __syncthreads();
        for (int f = tid; f < 128 * 16; f += WG) {
            int r = f >> 4, c = f & 15;
            *(float4*)&Bs[r][c * 8] = *(const float4*)(W1t + (size_t)r * 256 + ph * 128 + c * 8);
        }
        __syncthreads();
#pragma unroll
        for (int t = 0; t < 8; ++t) acc[t] = (f32x4){0.f, 0.f, 0.f, 0.f};
#pragma unroll
        for (int kk = 0; kk < 4; ++kk) {
            f16x8 af = *(f16x8*)&As[wv * 16 + m][kk * 32 + quad * 8];
#pragma unroll
            for (int t = 0; t < 8; ++t) {
                f16x8 bf = *(f16x8*)&Bs[t * 16 + m][kk * 32 + quad * 8];
                acc[t] = __builtin_amdgcn_mfma_f32_16x16x32_f16(af, bf, acc[t], 0, 0, 0);
            }
        }
        __half2* Out = ph ? Vp : Up;
#pragma unroll
        for (int t = 0; t < 4; ++t) {
            float bl = 0.f, bh = 0.f;
            if (!ph) { bl = b1[t * 16 + m]; bh = b1[t * 16 + m + 64]; }
#pragma unroll
            for (int r = 0; r < 4; ++r) {
                int row = row0 + wv * 16 + quad * 4 + r;
                if (row < n)
                    Out[(size_t)row * 64 + t * 16 + m] =
                        __floats2half2_rn(acc[t][r] + bl, acc[t + 4][r] + bh);
            }
        }
    }
}

// ------------- gather: out_h[d] = (sum_in Hpk'[s] + Hpk'[d]) * dinv[d] + b
// Hpk' rows premultiplied by dinv[s]. 16 lanes/node, lane owns 8 cols (int4).
__global__ __launch_bounds__(WG) void k_gather(const __half2* __restrict__ Hpk,
                                               const float* __restrict__ dinv,
                                               const float* __restrict__ bg,
                                               const int* __restrict__ base,
                                               const int* __restrict__ esrc,
                                               float* __restrict__ outh, int n) {
    int tid = threadIdx.x;
    int node = blockIdx.x * 16 + (tid >> 4);
    int sub = tid & 15;
    if (node >= n) return;
    int4 hh = *(const int4*)(Hpk + (size_t)node * 64 + 4 * sub);
    const int* hp = (const int*)&hh;
    float accl[4], acch[4];
#pragma unroll
    for (int k = 0; k < 4; ++k) {
        hv2 h = __builtin_bit_cast(hv2, hp[k]);
        accl[k] = (float)h[0];
        acch[k] = (float)h[1];
    }
    int j = base[node], jend = base[node + 1];
    for (; j + 4 <= jend; j += 4) {
        int s0 = esrc[j], s1 = esrc[j + 1], s2i = esrc[j + 2], s3 = esrc[j + 3];
        int4 r0 = *(const int4*)(Hpk + (size_t)s0 * 64 + 4 * sub);
        int4 r1 = *(const int4*)(Hpk + (size_t)s1 * 64 + 4 * sub);
        int4 r2 = *(const int4*)(Hpk + (size_t)s2i * 64 + 4 * sub);
        int4 r3 = *(const int4*)(Hpk + (size_t)s3 * 64 + 4 * sub);
        const int* p0 = (const int*)&r0;
        const int* p1 = (const int*)&r1;
        const int* p2 = (const int*)&r2;
        const int* p3 = (const int*)&r3;
#pragma unroll
        for (int k = 0; k < 4; ++k) {
            hv2 h0 = __builtin_bit_cast(hv2, p0[k]);
            hv2 h1 = __builtin_bit_cast(hv2, p1[k]);
            hv2 h2 = __builtin_bit_cast(hv2, p2[k]);
            hv2 h3 = __builtin_bit_cast(hv2, p3[k]);
            accl[k] += (float)h0[0] + (float)h1[0] + (float)h2[0] + (float)h3[0];
            acch[k] += (float)h0[1] + (float)h1[1] + (float)h2[1] + (float)h3[1];
        }
    }
    for (; j < jend; ++j) {
        int s = esrc[j];
        int4 r = *(const int4*)(Hpk + (size_t)s * 64 + 4 * sub);
        const int* pr = (const int*)&r;
#pragma unroll
        for (int k = 0; k < 4; ++k) {
            hv2 h = __builtin_bit_cast(hv2, pr[k]);
            accl[k] += (float)h[0];
            acch[k] += (float)h[1];
        }
    }
    float dv = dinv[node];
    float4 blo = *(const float4*)(bg + 4 * sub);
    float4 bhi = *(const float4*)(bg + 4 * sub + 64);
    *(float4*)&outh[(size_t)node * 128 + 4 * sub] =
        make_float4(fmaf(accl[0], dv, blo.x), fmaf(accl[1], dv, blo.y),
                    fmaf(accl[2], dv, blo.z), fmaf(accl[3], dv, blo.w));
    *(float4*)&outh[(size_t)node * 128 + 64 + 4 * sub] =
        make_float4(fmaf(acch[0], dv, bhi.x), fmaf(acch[1], dv, bhi.y),
                    fmaf(acch[2], dv, bhi.z), fmaf(acch[3], dv, bhi.w));
}

// --------- 2 pairs per 16-lane group (8/wave): logit = relu(U[a]+V[b]).W2 + b2
__global__ __launch_bounds__(WG) void k_pair8(const __half2* __restrict__ U,
                                              const __half2* __restrict__ V,
                                              const float* __restrict__ W2,
                                              const float* __restrict__ b2,
                                              const int* __restrict__ pairs,
                                              float* __restrict__ out_logit, int p) {
    int wv = (blockIdx.x * WG + threadIdx.x) >> 6;
    int lane = threadIdx.x & 63;
    int g = lane >> 4, sub = lane & 15;
    int q0 = wv * 8 + g, q1 = q0 + 4;
    bool v0 = (q0 < p), v1 = (q1 < p);
    if (!v0) return;
    int qa0 = q0, qa1 = v1 ? q1 : q0;
    int a0 = pairs[2 * qa0], b0 = pairs[2 * qa0 + 1];
    int a1 = pairs[2 * qa1], b1i = pairs[2 * qa1 + 1];

    float4 w2lo = ((const float4*)W2)[sub];
    float4 w2hi = ((const float4*)(W2 + 64))[sub];
    hv2 w2h[4];
    w2h[0] = hv2{(f16)w2lo.x, (f16)w2hi.x};
    w2h[1] = hv2{(f16)w2lo.y, (f16)w2hi.y};
    w2h[2] = hv2{(f16)w2lo.z, (f16)w2hi.z};
    w2h[3] = hv2{(f16)w2lo.w, (f16)w2hi.w};

    int4 u0 = *(const int4*)(U + (size_t)a0 * 64 + 4 * sub);
    int4 vv0 = *(const int4*)(V + (size_t)b0 * 64 + 4 * sub);
    int4 u1 = *(const int4*)(U + (size_t)a1 * 64 + 4 * sub);
    int4 vv1 = *(const int4*)(V + (size_t)b1i * 64 + 4 * sub);
    const int* ui0 = (const int*)&u0;
    const int* vi0 = (const int*)&vv0;
    const int* ui1 = (const int*)&u1;
    const int* vi1 = (const int*)&vv1;

    const hv2 z2 = hv2{(f16)0.f, (f16)0.f};
    float p0 = 0.f, p1 = 0.f;
#pragma unroll
    for (int k = 0; k < 4; ++k) {
        hv2 s0 = __builtin_bit_cast(hv2, ui0[k]) + __builtin_bit_cast(hv2, vi0[k]);
        hv2 s1 = __builtin_bit_cast(hv2, ui1[k]) + __builtin_bit_cast(hv2, vi1[k]);
        p0 = __builtin_amdgcn_fdot2(__builtin_elementwise_max(s0, z2), w2h[k], p0, false);
        p1 = __builtin_amdgcn_fdot2(__builtin_elementwise_max(s1, z2), w2h[k], p1, false);
    }
#pragma unroll
    for (int m = 1; m < 16; m <<= 1) {
        p0 += __shfl_xor(p0, m, 64);
        p1 += __shfl_xor(p1, m, 64);
    }
    if (sub == 0) {
        float bb = b2[0];
        out_logit[q0] = p0 + bb;
        if (v1) out_logit[q1] = p1 + bb;
    }
}

// --------- out_pairs[i] = (float)pairs[i], vectorized
__global__ __launch_bounds__(WG) void k_cvtpairs(const int* __restrict__ pairs,
                                                 float* __restrict__ outp, int n4) {
    int i = blockIdx.x * WG + threadIdx.x;
    if (i >= n4) return;
    int4 v = ((const int4*)pairs)[i];
    ((float4*)outp)[i] = make_float4((float)v.x, (float)v.y, (float)v.z, (float)v.w);
}

extern "C" void kernel_launch(void* const* d_in, const int* in_sizes, int n_in,
                              void* d_out, int out_size, void* d_ws, size_t ws_size,
                              hipStream_t stream) {
    const float* x     = (const float*)d_in[0];
    const int*   eidx  = (const int*)d_in[1];
    const int*   pairs = (const int*)d_in[2];
    const float* W_gcn = (const float*)d_in[3];
    const float* b_gcn = (const float*)d_in[4];
    const float* W1    = (const float*)d_in[5];
    const float* b1    = (const float*)d_in[6];
    const float* W2    = (const float*)d_in[7];
    const float* b2    = (const float*)d_in[8];

    const int N = in_sizes[0] / 128;
    const int E = in_sizes[1] / 2;
    const int P = in_sizes[2] / 2;
    const int* esrc_in = eidx;
    const int* edst_in = eidx + E;

    // workspace layout (4-byte units)
    float* ws      = (float*)d_ws;
    int*   deg     = (int*)d_ws;                  // [N]
    float* dinv    = ws + 65536;                  // [N]
    int*   base    = (int*)(ws + 131072);         // [N+1]
    int*   cursor  = (int*)(ws + 196608);         // [N]
    int*   bsum    = (int*)(ws + 262144);         // [256]
    f16*   Wt_gcn  = (f16*)(ws + 262400);         // [128*128] f16
    f16*   W1t     = (f16*)(ws + 270592);         // [128*256] f16
    int*   ecsr    = (int*)(ws + 287744);         // [E]
    __half2* Hpk   = (__half2*)(ws + 287744 + (size_t)E);  // [N*64]
    __half2* Upk   = Hpk + (size_t)N * 64;        // [N*64]
    __half2* Vpk   = Upk + (size_t)N * 64;        // [N*64]

    float* out_logit = (float*)d_out;             // [P]
    float* out_pairs = out_logit + P;             // [2P] as float
    float* out_h     = out_logit + 3 * (size_t)P; // [N*128]

    const int nb = (N + WG - 1) / WG;  // 196 <= 256
    dim3 blk(WG);
    dim3 grid_pair((unsigned)((P + 31) / 32));
    hipMemsetAsync(deg, 0, (size_t)N * 4, stream);
    k_deg_count <<<(E + WG - 1) / WG, blk, 0, stream>>>(edst_in, deg, E);
    k_scan1     <<<nb, blk, 0, stream>>>(deg, dinv, base, bsum, N);
    k_scan2     <<<1,  blk, 0, stream>>>(bsum, nb);
    k_scan3     <<<nb, blk, 0, stream>>>(base, bsum, cursor, N, E);
    k_fill      <<<(E + WG - 1) / WG, blk, 0, stream>>>(esrc_in, edst_in, cursor, ecsr, E);
    k_transpose <<<(128 * 128) / WG, blk, 0, stream>>>(W_gcn, Wt_gcn, 7);
    k_transpose <<<(128 * 256) / WG, blk, 0, stream>>>(W1, W1t, 8);
    k_mm_hpk    <<<(N + 63) / 64, blk, 0, stream>>>(x, Wt_gcn, dinv, Hpk, N);
    k_gather    <<<(N + 15) / 16, blk, 0, stream>>>(Hpk, dinv, b_gcn, base, ecsr, out_h, N);
    k_mm_uv     <<<(N + 63) / 64, blk, 0, stream>>>(out_h, W1t, b1, Upk, Vpk, N);
    k_cvtpairs  <<<(P / 2 + WG - 1) / WG, blk, 0, stream>>>(pairs, out_pairs, P / 2);
    k_pair8     <<<grid_pair, blk, 0, stream>>>(Upk, Vpk, W2, b2, pairs, out_logit, P);
}

// Round 10
// 277.194 us; speedup vs baseline: 2.8060x; 1.1412x over previous
//
#include <hip/hip_runtime.h>
#include <hip/hip_fp16.h>

#define WG 256

typedef _Float16 f16;
typedef _Float16 hv2 __attribute__((ext_vector_type(2)));
typedef _Float16 f16x4 __attribute__((ext_vector_type(4)));
typedef _Float16 f16x8 __attribute__((ext_vector_type(8)));
typedef float f32x4 __attribute__((ext_vector_type(4)));

// ------------- degree + per-edge rank (CSR slot = base[dst] + rank)
__global__ __launch_bounds__(WG) void k_deg_count(const int* __restrict__ dst,
                                                  int* __restrict__ deg,
                                                  int* __restrict__ rank, int e) {
    int i = blockIdx.x * WG + threadIdx.x;
    if (i < e) rank[i] = atomicAdd(&deg[dst[i]], 1);
}

// ------------------------------------------------ CSR build
// deg[] holds pure in-degree (self-loop handled via +1 for dinv).
__global__ __launch_bounds__(WG) void k_scan1(const int* __restrict__ deg,
                                              float* __restrict__ dinv,
                                              int* __restrict__ base,
                                              int* __restrict__ bsum, int n) {
    __shared__ int t[WG];
    int tid = threadIdx.x;
    int i = blockIdx.x * WG + tid;
    int v = (i < n) ? deg[i] : 0;
    if (i < n) dinv[i] = rsqrtf((float)(v + 1));
    t[tid] = v;
    __syncthreads();
    for (int o = 1; o < WG; o <<= 1) {
        int add = (tid >= o) ? t[tid - o] : 0;
        __syncthreads();
        t[tid] += add;
        __syncthreads();
    }
    if (i < n) base[i] = t[tid] - v;  // block-local exclusive
    if (tid == WG - 1) bsum[blockIdx.x] = t[WG - 1];
}

// fused scan2+scan3: each block scans bsum in LDS, adds its own prefix.
__global__ __launch_bounds__(WG) void k_scan23(int* __restrict__ base,
                                               const int* __restrict__ bsum,
                                               int n, int e, int nb) {
    __shared__ int t[WG];
    int tid = threadIdx.x;
    int v = (tid < nb) ? bsum[tid] : 0;
    t[tid] = v;
    __syncthreads();
    for (int o = 1; o < WG; o <<= 1) {
        int add = (tid >= o) ? t[tid - o] : 0;
        __syncthreads();
        t[tid] += add;
        __syncthreads();
    }
    int off = t[blockIdx.x] - ((blockIdx.x < nb) ? bsum[blockIdx.x] : 0);
    int i = blockIdx.x * WG + tid;
    if (i < n) {
        base[i] += off;
        if (i == n - 1) base[n] = e;
    }
}

// ---------------- fill: no atomics — slot precomputed by rank
__global__ __launch_bounds__(WG) void k_fill(const int* __restrict__ src,
                                             const int* __restrict__ dst,
                                             const int* __restrict__ base,
                                             const int* __restrict__ rank,
                                             int* __restrict__ esrc, int e) {
    int i = blockIdx.x * WG + threadIdx.x;
    if (i >= e) return;
    esrc[base[dst[i]] + rank[i]] = src[i];
}

// ---------- misc grid-fused: transpose W_gcn (f16), transpose W1 (f16), cvt pairs
__global__ __launch_bounds__(WG) void k_misc(const float* __restrict__ Wg,
                                             f16* __restrict__ Wgt,
                                             const float* __restrict__ W1,
                                             f16* __restrict__ W1t,
                                             const int* __restrict__ pairs,
                                             float* __restrict__ outp, int n4) {
    int b = blockIdx.x;
    if (b < 64) {  // Wgt[n*128+k] = Wg[k*128+n]
        int i = b * WG + threadIdx.x;
        int k = i & 127, nI = i >> 7;
        Wgt[i] = (f16)Wg[(size_t)k * 128 + nI];
    } else if (b < 192) {  // W1t[n*256+k] = W1[k*128+n]
        int i = (b - 64) * WG + threadIdx.x;
        int k = i & 255, nI = i >> 8;
        W1t[i] = (f16)W1[(size_t)k * 128 + nI];
    } else {
        int i = (b - 192) * WG + threadIdx.x;
        if (i < n4) {
            int4 v = ((const int4*)pairs)[i];
            ((float4*)outp)[i] = make_float4((float)v.x, (float)v.y, (float)v.z, (float)v.w);
        }
    }
}

// ---------- MFMA GEMM: Hpk'[r][c] = half2 of (A@W)[r][{c,c+64}] * dinv[r]
__global__ __launch_bounds__(WG) void k_mm_hpk(const float* __restrict__ A,
                                               const f16* __restrict__ Wt,  // [128][128]
                                               const float* __restrict__ dinv,
                                               __half2* __restrict__ Out, int n) {
    __shared__ f16 As[64][136];
    __shared__ f16 Bs[128][136];
    const int tid = threadIdx.x;
    const int row0 = blockIdx.x * 64;
    for (int f = tid; f < 128 * 16; f += WG) {
        int r = f >> 4, c = f & 15;
        *(float4*)&Bs[r][c * 8] = ((const float4*)Wt)[r * 16 + c];
    }
    for (int f = tid; f < 64 * 32; f += WG) {
        int r = f >> 5, c = f & 31;
        float4 v = make_float4(0.f, 0.f, 0.f, 0.f);
        if (row0 + r < n) v = ((const float4*)A)[(size_t)(row0 + r) * 32 + c];
        *(f16x4*)&As[r][c * 4] = (f16x4){(f16)v.x, (f16)v.y, (f16)v.z, (f16)v.w};
    }
    __syncthreads();
    const int wv = tid >> 6, lane = tid & 63, m = lane & 15, quad = lane >> 4;
    f32x4 acc[8];
#pragma unroll
    for (int t = 0; t < 8; ++t) acc[t] = (f32x4){0.f, 0.f, 0.f, 0.f};
#pragma unroll
    for (int kk = 0; kk < 4; ++kk) {
        f16x8 af = *(f16x8*)&As[wv * 16 + m][kk * 32 + quad * 8];
#pragma unroll
        for (int t = 0; t < 8; ++t) {
            f16x8 bf = *(f16x8*)&Bs[t * 16 + m][kk * 32 + quad * 8];
            acc[t] = __builtin_amdgcn_mfma_f32_16x16x32_f16(af, bf, acc[t], 0, 0, 0);
        }
    }
#pragma unroll
    for (int r = 0; r < 4; ++r) {
        int row = row0 + wv * 16 + quad * 4 + r;
        if (row < n) {
            float dv = dinv[row];
#pragma unroll
            for (int t = 0; t < 4; ++t)
                Out[(size_t)row * 64 + t * 16 + m] =
                    __floats2half2_rn(acc[t][r] * dv, acc[t + 4][r] * dv);
        }
    }
}

// ---------- Fused U/V MFMA GEMM: U = A@W1a + b1, V = A@W1b; packed (c, c+64)
__global__ __launch_bounds__(WG) void k_mm_uv(const float* __restrict__ A,
                                              const f16* __restrict__ W1t,
                                              const float* __restrict__ b1,
                                              __half2* __restrict__ Up,
                                              __half2* __restrict__ Vp, int n) {
    __shared__ f16 As[64][136];
    __shared__ f16 Bs[128][136];
    const int tid = threadIdx.x;
    const int row0 = blockIdx.x * 64;
    for (int f = tid; f < 64 * 32; f += WG) {
        int r = f >> 5, c = f & 31;
        float4 v = make_float4(0.f, 0.f, 0.f, 0.f);
        if (row0 + r < n) v = ((const float4*)A)[(size_t)(row0 + r) * 32 + c];
        *(f16x4*)&As[r][c * 4] = (f16x4){(f16)v.x, (f16)v.y, (f16)v.z, (f16)v.w};
    }
    const int wv = tid >> 6, lane = tid & 63, m = lane & 15, quad = lane >> 4;
    f32x4 acc[8];
#pragma unroll
    for (int ph = 0; ph < 2; ++ph) {
        if (ph) __syncthreads();
        for (int f = tid; f < 128 * 16; f += WG) {
            int r = f >> 4, c = f & 15;
            *(float4*)&Bs[r][c * 8] = *(const float4*)(W1t + (size_t)r * 256 + ph * 128 + c * 8);
        }
        __syncthreads();
#pragma unroll
        for (int t = 0; t < 8; ++t) acc[t] = (f32x4){0.f, 0.f, 0.f, 0.f};
#pragma unroll
        for (int kk = 0; kk < 4; ++kk) {
            f16x8 af = *(f16x8*)&As[wv * 16 + m][kk * 32 + quad * 8];
#pragma unroll
            for (int t = 0; t < 8; ++t) {
                f16x8 bf = *(f16x8*)&Bs[t * 16 + m][kk * 32 + quad * 8];
                acc[t] = __builtin_amdgcn_mfma_f32_16x16x32_f16(af, bf, acc[t], 0, 0, 0);
            }
        }
        __half2* Out = ph ? Vp : Up;
#pragma unroll
        for (int t = 0; t < 4; ++t) {
            float bl = 0.f, bh = 0.f;
            if (!ph) { bl = b1[t * 16 + m]; bh = b1[t * 16 + m + 64]; }
#pragma unroll
            for (int r = 0; r < 4; ++r) {
                int row = row0 + wv * 16 + quad * 4 + r;
                if (row < n)
                    Out[(size_t)row * 64 + t * 16 + m] =
                        __floats2half2_rn(acc[t][r] + bl, acc[t + 4][r] + bh);
            }
        }
    }
}

// ------------- gather: out_h[d] = (sum_in Hpk'[s] + Hpk'[d]) * dinv[d] + b
__global__ __launch_bounds__(WG) void k_gather(const __half2* __restrict__ Hpk,
                                               const float* __restrict__ dinv,
                                               const float* __restrict__ bg,
                                               const int* __restrict__ base,
                                               const int* __restrict__ esrc,
                                               float* __restrict__ outh, int n) {
    int tid = threadIdx.x;
    int node = blockIdx.x * 16 + (tid >> 4);
    int sub = tid & 15;
    if (node >= n) return;
    int4 hh = *(const int4*)(Hpk + (size_t)node * 64 + 4 * sub);
    const int* hp = (const int*)&hh;
    float accl[4], acch[4];
#pragma unroll
    for (int k = 0; k < 4; ++k) {
        hv2 h = __builtin_bit_cast(hv2, hp[k]);
        accl[k] = (float)h[0];
        acch[k] = (float)h[1];
    }
    int j = base[node], jend = base[node + 1];
    for (; j + 4 <= jend; j += 4) {
        int s0 = esrc[j], s1 = esrc[j + 1], s2i = esrc[j + 2], s3 = esrc[j + 3];
        int4 r0 = *(const int4*)(Hpk + (size_t)s0 * 64 + 4 * sub);
        int4 r1 = *(const int4*)(Hpk + (size_t)s1 * 64 + 4 * sub);
        int4 r2 = *(const int4*)(Hpk + (size_t)s2i * 64 + 4 * sub);
        int4 r3 = *(const int4*)(Hpk + (size_t)s3 * 64 + 4 * sub);
        const int* p0 = (const int*)&r0;
        const int* p1 = (const int*)&r1;
        const int* p2 = (const int*)&r2;
        const int* p3 = (const int*)&r3;
#pragma unroll
        for (int k = 0; k < 4; ++k) {
            hv2 h0 = __builtin_bit_cast(hv2, p0[k]);
            hv2 h1 = __builtin_bit_cast(hv2, p1[k]);
            hv2 h2 = __builtin_bit_cast(hv2, p2[k]);
            hv2 h3 = __builtin_bit_cast(hv2, p3[k]);
            accl[k] += (float)h0[0] + (float)h1[0] + (float)h2[0] + (float)h3[0];
            acch[k] += (float)h0[1] + (float)h1[1] + (float)h2[1] + (float)h3[1];
        }
    }
    for (; j < jend; ++j) {
        int s = esrc[j];
        int4 r = *(const int4*)(Hpk + (size_t)s * 64 + 4 * sub);
        const int* pr = (const int*)&r;
#pragma unroll
        for (int k = 0; k < 4; ++k) {
            hv2 h = __builtin_bit_cast(hv2, pr[k]);
            accl[k] += (float)h[0];
            acch[k] += (float)h[1];
        }
    }
    float dv = dinv[node];
    float4 blo = *(const float4*)(bg + 4 * sub);
    float4 bhi = *(const float4*)(bg + 4 * sub + 64);
    *(float4*)&outh[(size_t)node * 128 + 4 * sub] =
        make_float4(fmaf(accl[0], dv, blo.x), fmaf(accl[1], dv, blo.y),
                    fmaf(accl[2], dv, blo.z), fmaf(accl[3], dv, blo.w));
    *(float4*)&outh[(size_t)node * 128 + 64 + 4 * sub] =
        make_float4(fmaf(acch[0], dv, bhi.x), fmaf(acch[1], dv, bhi.y),
                    fmaf(acch[2], dv, bhi.z), fmaf(acch[3], dv, bhi.w));
}

// --------- 2 pairs per 16-lane group (8/wave): logit = relu(U[a]+V[b]).W2 + b2
__global__ __launch_bounds__(WG) void k_pair8(const __half2* __restrict__ U,
                                              const __half2* __restrict__ V,
                                              const float* __restrict__ W2,
                                              const float* __restrict__ b2,
                                              const int* __restrict__ pairs,
                                              float* __restrict__ out_logit, int p) {
    int wv = (blockIdx.x * WG + threadIdx.x) >> 6;
    int lane = threadIdx.x & 63;
    int g = lane >> 4, sub = lane & 15;
    int q0 = wv * 8 + g, q1 = q0 + 4;
    bool v0 = (q0 < p), v1 = (q1 < p);
    if (!v0) return;
    int qa0 = q0, qa1 = v1 ? q1 : q0;
    int a0 = pairs[2 * qa0], b0 = pairs[2 * qa0 + 1];
    int a1 = pairs[2 * qa1], b1i = pairs[2 * qa1 + 1];

    float4 w2lo = ((const float4*)W2)[sub];
    float4 w2hi = ((const float4*)(W2 + 64))[sub];
    hv2 w2h[4];
    w2h[0] = hv2{(f16)w2lo.x, (f16)w2hi.x};
    w2h[1] = hv2{(f16)w2lo.y, (f16)w2hi.y};
    w2h[2] = hv2{(f16)w2lo.z, (f16)w2hi.z};
    w2h[3] = hv2{(f16)w2lo.w, (f16)w2hi.w};

    int4 u0 = *(const int4*)(U + (size_t)a0 * 64 + 4 * sub);
    int4 vv0 = *(const int4*)(V + (size_t)b0 * 64 + 4 * sub);
    int4 u1 = *(const int4*)(U + (size_t)a1 * 64 + 4 * sub);
    int4 vv1 = *(const int4*)(V + (size_t)b1i * 64 + 4 * sub);
    const int* ui0 = (const int*)&u0;
    const int* vi0 = (const int*)&vv0;
    const int* ui1 = (const int*)&u1;
    const int* vi1 = (const int*)&vv1;

    const hv2 z2 = hv2{(f16)0.f, (f16)0.f};
    float p0 = 0.f, p1 = 0.f;
#pragma unroll
    for (int k = 0; k < 4; ++k) {
        hv2 s0 = __builtin_bit_cast(hv2, ui0[k]) + __builtin_bit_cast(hv2, vi0[k]);
        hv2 s1 = __builtin_bit_cast(hv2, ui1[k]) + __builtin_bit_cast(hv2, vi1[k]);
        p0 = __builtin_amdgcn_fdot2(__builtin_elementwise_max(s0, z2), w2h[k], p0, false);
        p1 = __builtin_amdgcn_fdot2(__builtin_elementwise_max(s1, z2), w2h[k], p1, false);
    }
#pragma unroll
    for (int m = 1; m < 16; m <<= 1) {
        p0 += __shfl_xor(p0, m, 64);
        p1 += __shfl_xor(p1, m, 64);
    }
    if (sub == 0) {
        float bb = b2[0];
        out_logit[q0] = p0 + bb;
        if (v1) out_logit[q1] = p1 + bb;
    }
}

extern "C" void kernel_launch(void* const* d_in, const int* in_sizes, int n_in,
                              void* d_out, int out_size, void* d_ws, size_t ws_size,
                              hipStream_t stream) {
    const float* x     = (const float*)d_in[0];
    const int*   eidx  = (const int*)d_in[1];
    const int*   pairs = (const int*)d_in[2];
    const float* W_gcn = (const float*)d_in[3];
    const float* b_gcn = (const float*)d_in[4];
    const float* W1    = (const float*)d_in[5];
    const float* b1    = (const float*)d_in[6];
    const float* W2    = (const float*)d_in[7];
    const float* b2    = (const float*)d_in[8];

    const int N = in_sizes[0] / 128;
    const int E = in_sizes[1] / 2;
    const int P = in_sizes[2] / 2;
    const int* esrc_in = eidx;
    const int* edst_in = eidx + E;

    // workspace layout (4-byte units)
    float* ws      = (float*)d_ws;
    int*   deg     = (int*)d_ws;                  // [N]
    float* dinv    = ws + 65536;                  // [N]
    int*   base    = (int*)(ws + 131072);         // [N+1]
    int*   bsum    = (int*)(ws + 196608);         // [256]
    f16*   Wt_gcn  = (f16*)(ws + 197120);         // [128*128] f16 = 8192 floats
    f16*   W1t     = (f16*)(ws + 205312);         // [128*256] f16 = 16384 floats
    int*   rank    = (int*)(ws + 221696);         // [E]
    int*   ecsr    = (int*)(ws + 221696 + (size_t)E);  // [E]
    __half2* Hpk   = (__half2*)(ws + 221696 + 2 * (size_t)E);  // [N*64]
    __half2* Upk   = Hpk + (size_t)N * 64;        // [N*64]
    __half2* Vpk   = Upk + (size_t)N * 64;        // [N*64]

    float* out_logit = (float*)d_out;             // [P]
    float* out_pairs = out_logit + P;             // [2P] as float
    float* out_h     = out_logit + 3 * (size_t)P; // [N*128]

    const int nb = (N + WG - 1) / WG;  // 196 <= 256
    dim3 blk(WG);
    dim3 grid_pair((unsigned)((P + 31) / 32));
    dim3 grid_misc((unsigned)(192 + (P / 2 + WG - 1) / WG));
    hipMemsetAsync(deg, 0, (size_t)N * 4, stream);
    k_deg_count <<<(E + WG - 1) / WG, blk, 0, stream>>>(edst_in, deg, rank, E);
    k_scan1     <<<nb, blk, 0, stream>>>(deg, dinv, base, bsum, N);
    k_scan23    <<<nb, blk, 0, stream>>>(base, bsum, N, E, nb);
    k_fill      <<<(E + WG - 1) / WG, blk, 0, stream>>>(esrc_in, edst_in, base, rank, ecsr, E);
    k_misc      <<<grid_misc, blk, 0, stream>>>(W_gcn, Wt_gcn, W1, W1t, pairs, out_pairs, P / 2);
    k_mm_hpk    <<<(N + 63) / 64, blk, 0, stream>>>(x, Wt_gcn, dinv, Hpk, N);
    k_gather    <<<(N + 15) / 16, blk, 0, stream>>>(Hpk, dinv, b_gcn, base, ecsr, out_h, N);
    k_mm_uv     <<<(N + 63) / 64, blk, 0, stream>>>(out_h, W1t, b1, Upk, Vpk, N);
    k_pair8     <<<grid_pair, blk, 0, stream>>>(Upk, Vpk, W2, b2, pairs, out_logit, P);
}